// Round 1
// baseline (2865.668 us; speedup 1.0000x reference)
//
#include <hip/hip_runtime.h>

#define N_NODES 100000
#define N_EDGES 1600000

// ---------------- degree / inverse ----------------
__global__ __launch_bounds__(256) void degree_kernel(const int* __restrict__ dst,
                                                     int* __restrict__ cnt, int E) {
    int i = blockIdx.x * blockDim.x + threadIdx.x;
    int stride = gridDim.x * blockDim.x;
    for (; i < E; i += stride) atomicAdd(&cnt[dst[i]], 1);
}

__global__ __launch_bounds__(256) void inv_kernel(const int* __restrict__ cnt,
                                                  float* __restrict__ inv, int N) {
    int i = blockIdx.x * blockDim.x + threadIdx.x;
    if (i < N) inv[i] = 1.0f / (float)max(cnt[i], 1);
}

// ---------------- node finish: out = acc * inv (+relu) ----------------
template <int D, bool RELU>
__global__ __launch_bounds__(256) void node_finish(const float* __restrict__ acc,
                                                   const float* __restrict__ inv,
                                                   float* __restrict__ out, int N) {
    int i = blockIdx.x * blockDim.x + threadIdx.x;  // over N*D/4 float4s
    int total = N * D / 4;
    if (i >= total) return;
    float4 v = ((const float4*)acc)[i];
    int n = (i * 4) / D;
    float s = inv[n];
    v.x *= s; v.y *= s; v.z *= s; v.w *= s;
    if (RELU) {
        v.x = fmaxf(v.x, 0.0f); v.y = fmaxf(v.y, 0.0f);
        v.z = fmaxf(v.z, 0.0f); v.w = fmaxf(v.w, 0.0f);
    }
    ((float4*)out)[i] = v;
}

// ---------------- fused per-edge 2-layer MLP + atomic scatter ----------------
// msg = [x[src] (IN_D), edge_attr (3)]  -> relu(msg@Wa+ba) @ Wb + bb -> atomicAdd at dst
// One wave handles 64/D edges at a time. Lane owns output column c = lane%D:
// holds Wa[:,c], Wb[:,c] in registers; msg broadcast from LDS via float4 reads.
template <int IN_D, int D>
__global__ __launch_bounds__(256) void edge_mlp(
    const float* __restrict__ xn,  // [N, IN_D]
    const float* __restrict__ ea,  // [E, 3]
    const int* __restrict__ src, const int* __restrict__ dst,
    const float* __restrict__ Wa,  // [IN_D+3, D]
    const float* __restrict__ ba,  // [D]
    const float* __restrict__ Wb,  // [D, D]
    const float* __restrict__ bb,  // [D]
    float* __restrict__ acc,       // [N, D]
    int E) {
    constexpr int M   = IN_D + 3;
    constexpr int M4  = (M + 3) & ~3;  // padded to float4
    constexpr int EPW = 64 / D;        // edges per wave
    constexpr int EPB = 4 * EPW;       // edges per block-iteration (4 waves)

    const int lane = threadIdx.x & 63;
    const int wave = threadIdx.x >> 6;
    const int c    = lane % D;
    const int esub = lane / D;

    __shared__ __align__(16) float smsg[4][EPW][M4];
    __shared__ __align__(16) float sh1[4][EPW][D];

    // per-lane weight columns (fully unrolled -> registers)
    float wa[M4];
#pragma unroll
    for (int k = 0; k < M4; ++k) wa[k] = (k < M) ? Wa[k * D + c] : 0.0f;
    float wb[D];
#pragma unroll
    for (int k = 0; k < D; ++k) wb[k] = Wb[k * D + c];
    const float bias_a = ba[c];
    const float bias_b = bb[c];

    const int perIter = gridDim.x * EPB;
    const int nIter   = (E + perIter - 1) / perIter;

    for (int it = 0; it < nIter; ++it) {
        const int blockBase = (it * gridDim.x + blockIdx.x) * EPB;
        const int waveBase  = blockBase + wave * EPW;

        // cooperative gather of this wave's EPW messages into LDS (zero-padded)
        for (int t = lane; t < EPW * M4; t += 64) {
            const int sub = t / M4;
            const int k   = t % M4;
            const int e   = waveBase + sub;
            float v = 0.0f;
            if (e < E && k < M) {
                v = (k < IN_D) ? xn[(long long)src[e] * IN_D + k]
                               : ea[(long long)e * 3 + (k - IN_D)];
            }
            smsg[wave][sub][k] = v;
        }
        __syncthreads();

        // first linear + relu: h1[c] = relu(sum_k msg[k]*Wa[k][c] + ba[c])
        float a0 = 0.f, a1 = 0.f, a2 = 0.f, a3 = 0.f;
#pragma unroll
        for (int q = 0; q < M4 / 4; ++q) {
            const float4 m = *(const float4*)&smsg[wave][esub][q * 4];
            a0 = fmaf(m.x, wa[q * 4 + 0], a0);
            a1 = fmaf(m.y, wa[q * 4 + 1], a1);
            a2 = fmaf(m.z, wa[q * 4 + 2], a2);
            a3 = fmaf(m.w, wa[q * 4 + 3], a3);
        }
        const float h1 = fmaxf((a0 + a1) + (a2 + a3) + bias_a, 0.0f);
        sh1[wave][esub][c] = h1;
        __syncthreads();

        // second linear: h2[c] = sum_k h1[k]*Wb[k][c] + bb[c]
        float b0 = 0.f, b1 = 0.f, b2 = 0.f, b3 = 0.f;
#pragma unroll
        for (int q = 0; q < D / 4; ++q) {
            const float4 h = *(const float4*)&sh1[wave][esub][q * 4];
            b0 = fmaf(h.x, wb[q * 4 + 0], b0);
            b1 = fmaf(h.y, wb[q * 4 + 1], b1);
            b2 = fmaf(h.z, wb[q * 4 + 2], b2);
            b3 = fmaf(h.w, wb[q * 4 + 3], b3);
        }
        const float h2 = (b0 + b1) + (b2 + b3) + bias_b;

        const int e = waveBase + esub;
        if (e < E) atomicAdd(&acc[(long long)dst[e] * D + c], h2);
    }
}

extern "C" void kernel_launch(void* const* d_in, const int* in_sizes, int n_in,
                              void* d_out, int out_size, void* d_ws, size_t ws_size,
                              hipStream_t stream) {
    const float* x   = (const float*)d_in[0];
    const int*   ei  = (const int*)d_in[1];
    const float* ea  = (const float*)d_in[2];
    const float* W1a = (const float*)d_in[3];
    const float* b1a = (const float*)d_in[4];
    const float* W1b = (const float*)d_in[5];
    const float* b1b = (const float*)d_in[6];
    const float* W2a = (const float*)d_in[7];
    const float* b2a = (const float*)d_in[8];
    const float* W2b = (const float*)d_in[9];
    const float* b2b = (const float*)d_in[10];
    const float* W3a = (const float*)d_in[11];
    const float* b3a = (const float*)d_in[12];
    const float* W3b = (const float*)d_in[13];
    const float* b3b = (const float*)d_in[14];

    const int* src = ei;             // edge_index[0]
    const int* dst = ei + N_EDGES;   // edge_index[1]

    // workspace layout (bytes): cnt[N] int | inv[N] f32 | H[N*64] f32 | A[N*64] f32
    char*  ws  = (char*)d_ws;
    int*   cnt = (int*)ws;
    float* inv = (float*)(ws + 400000);
    float* H   = (float*)(ws + 800000);
    float* A   = (float*)(ws + 800000 + (size_t)N_NODES * 64 * 4);
    float* out = (float*)d_out;

    // degree + inverse
    hipMemsetAsync(cnt, 0, N_NODES * sizeof(int), stream);
    degree_kernel<<<2048, 256, 0, stream>>>(dst, cnt, N_EDGES);
    inv_kernel<<<(N_NODES + 255) / 256, 256, 0, stream>>>(cnt, inv, N_NODES);

    // ---- layer 1: IN=6, D=64 ----
    hipMemsetAsync(A, 0, (size_t)N_NODES * 64 * 4, stream);
    edge_mlp<6, 64><<<2048, 256, 0, stream>>>(x, ea, src, dst, W1a, b1a, W1b, b1b, A, N_EDGES);
    node_finish<64, true><<<(N_NODES * 64 / 4 + 255) / 256, 256, 0, stream>>>(A, inv, H, N_NODES);

    // ---- layer 2: IN=64, D=64 ----
    hipMemsetAsync(A, 0, (size_t)N_NODES * 64 * 4, stream);
    edge_mlp<64, 64><<<2048, 256, 0, stream>>>(H, ea, src, dst, W2a, b2a, W2b, b2b, A, N_EDGES);
    node_finish<64, true><<<(N_NODES * 64 / 4 + 255) / 256, 256, 0, stream>>>(A, inv, H, N_NODES);

    // ---- layer 3: IN=64, D=32 ----
    hipMemsetAsync(A, 0, (size_t)N_NODES * 32 * 4, stream);
    edge_mlp<64, 32><<<2048, 256, 0, stream>>>(H, ea, src, dst, W3a, b3a, W3b, b3b, A, N_EDGES);
    node_finish<32, false><<<(N_NODES * 32 / 4 + 255) / 256, 256, 0, stream>>>(A, inv, out, N_NODES);
}

// Round 2
// 1278.148 us; speedup vs baseline: 2.2420x; 2.2420x over previous
//
#include <hip/hip_runtime.h>

#define N_NODES 100000
#define N_EDGES 1600000

// ---------------- degree / inverse ----------------
__global__ __launch_bounds__(256) void degree_kernel(const int* __restrict__ dst,
                                                     int* __restrict__ cnt, int E) {
    int i = blockIdx.x * blockDim.x + threadIdx.x;
    int stride = gridDim.x * blockDim.x;
    for (; i < E; i += stride) atomicAdd(&cnt[dst[i]], 1);
}

__global__ __launch_bounds__(256) void inv_kernel(const int* __restrict__ cnt,
                                                  float* __restrict__ inv, int N) {
    int i = blockIdx.x * blockDim.x + threadIdx.x;
    if (i < N) inv[i] = 1.0f / (float)max(cnt[i], 1);
}

// ---------------- node finish: out = acc * inv (+relu) ----------------
template <int D, bool RELU>
__global__ __launch_bounds__(256) void node_finish(const float* __restrict__ acc,
                                                   const float* __restrict__ inv,
                                                   float* __restrict__ out, int N) {
    int i = blockIdx.x * blockDim.x + threadIdx.x;  // over N*D/4 float4s
    int total = N * D / 4;
    if (i >= total) return;
    float4 v = ((const float4*)acc)[i];
    int n = (i * 4) / D;
    float s = inv[n];
    v.x *= s; v.y *= s; v.z *= s; v.w *= s;
    if (RELU) {
        v.x = fmaxf(v.x, 0.0f); v.y = fmaxf(v.y, 0.0f);
        v.z = fmaxf(v.z, 0.0f); v.w = fmaxf(v.w, 0.0f);
    }
    ((float4*)out)[i] = v;
}

// ---------------- lane-per-edge fused 2-layer MLP + coalesced atomic scatter --
// Each THREAD owns one edge: msg[M] and h2[D] live in VGPRs. Weight accesses
// are lane-uniform -> compiler emits s_load + FMA-with-SGPR (no LDS, no
// barriers in the MLP). Scatter goes through a per-wave LDS transpose (no
// __syncthreads; wave-lockstep + compiler lgkmcnt) so each atomic instruction
// covers 4 dst rows x 64B contiguous.
template <int IN_D, int D>
__global__ __launch_bounds__(256) void edge_mlp(
    const float* __restrict__ xn,  // [N, IN_D]
    const float* __restrict__ ea,  // [E, 3]
    const int* __restrict__ src, const int* __restrict__ dst,
    const float* __restrict__ Wa,  // [M, D]
    const float* __restrict__ ba,  // [D]
    const float* __restrict__ Wb,  // [D, D]
    const float* __restrict__ bb,  // [D]
    float* __restrict__ acc,       // [N, D]
    int E) {
    constexpr int M = IN_D + 3;

    const int tid  = blockIdx.x * blockDim.x + threadIdx.x;
    const int lane = threadIdx.x & 63;
    const int wave = threadIdx.x >> 6;
    const int waveBase = blockIdx.x * 256 + wave * 64;

    const int  e      = tid;
    const bool valid  = (e < E);
    const int  eClamp = valid ? e : (E - 1);

    // ---- gather message into registers ----
    float msg[M];
    {
        const int s = src[eClamp];
        const float* xrow = xn + (size_t)s * IN_D;
        if constexpr ((IN_D & 3) == 0) {
#pragma unroll
            for (int q = 0; q < IN_D / 4; ++q) {
                float4 v = ((const float4*)xrow)[q];
                msg[q * 4 + 0] = v.x; msg[q * 4 + 1] = v.y;
                msg[q * 4 + 2] = v.z; msg[q * 4 + 3] = v.w;
            }
        } else {
#pragma unroll
            for (int k = 0; k < IN_D; ++k) msg[k] = xrow[k];
        }
#pragma unroll
        for (int k = 0; k < 3; ++k) msg[IN_D + k] = ea[(size_t)eClamp * 3 + k];
    }

    // ---- fused 2-layer MLP, h2[D] accumulators in registers ----
    float h2[D];
#pragma unroll
    for (int c = 0; c < D; ++c) h2[c] = bb[c];

    for (int g = 0; g < D / 4; ++g) {   // rolled: weights via uniform s_load
        float a0 = ba[g * 4 + 0], a1 = ba[g * 4 + 1];
        float a2 = ba[g * 4 + 2], a3 = ba[g * 4 + 3];
#pragma unroll
        for (int k = 0; k < M; ++k) {
            const float m = msg[k];
            const float* w = &Wa[k * D + g * 4];
            a0 = fmaf(m, w[0], a0);
            a1 = fmaf(m, w[1], a1);
            a2 = fmaf(m, w[2], a2);
            a3 = fmaf(m, w[3], a3);
        }
        a0 = fmaxf(a0, 0.0f); a1 = fmaxf(a1, 0.0f);
        a2 = fmaxf(a2, 0.0f); a3 = fmaxf(a3, 0.0f);
        const float* w0 = &Wb[(g * 4 + 0) * D];
        const float* w1 = &Wb[(g * 4 + 1) * D];
        const float* w2 = &Wb[(g * 4 + 2) * D];
        const float* w3 = &Wb[(g * 4 + 3) * D];
#pragma unroll
        for (int c = 0; c < D; ++c) {
            h2[c] = fmaf(a0, w0[c],
                    fmaf(a1, w1[c],
                    fmaf(a2, w2[c],
                    fmaf(a3, w3[c], h2[c]))));
        }
    }

    // ---- per-wave LDS transpose scatter (no __syncthreads needed) ----
    __shared__ float sh[4][64][17];
    const int myDst = dst[eClamp];
    const int sub = lane >> 4;   // 0..3
    const int col = lane & 15;   // 0..15

#pragma unroll
    for (int cc = 0; cc < D / 16; ++cc) {
#pragma unroll
        for (int j = 0; j < 16; ++j) sh[wave][lane][j] = h2[cc * 16 + j];
#pragma unroll
        for (int r = 0; r < 16; ++r) {
            const int e2 = r * 4 + sub;                 // edge slot in wave
            const float v = sh[wave][e2][col];
            const int dn = __shfl(myDst, e2);
            if (waveBase + e2 < E)
                atomicAdd(&acc[(size_t)dn * D + cc * 16 + col], v);
        }
    }
}

extern "C" void kernel_launch(void* const* d_in, const int* in_sizes, int n_in,
                              void* d_out, int out_size, void* d_ws, size_t ws_size,
                              hipStream_t stream) {
    const float* x   = (const float*)d_in[0];
    const int*   ei  = (const int*)d_in[1];
    const float* ea  = (const float*)d_in[2];
    const float* W1a = (const float*)d_in[3];
    const float* b1a = (const float*)d_in[4];
    const float* W1b = (const float*)d_in[5];
    const float* b1b = (const float*)d_in[6];
    const float* W2a = (const float*)d_in[7];
    const float* b2a = (const float*)d_in[8];
    const float* W2b = (const float*)d_in[9];
    const float* b2b = (const float*)d_in[10];
    const float* W3a = (const float*)d_in[11];
    const float* b3a = (const float*)d_in[12];
    const float* W3b = (const float*)d_in[13];
    const float* b3b = (const float*)d_in[14];

    const int* src = ei;             // edge_index[0]
    const int* dst = ei + N_EDGES;   // edge_index[1]

    // workspace layout (bytes): cnt[N] int | inv[N] f32 | H[N*64] f32 | A[N*64] f32
    char*  ws  = (char*)d_ws;
    int*   cnt = (int*)ws;
    float* inv = (float*)(ws + 400000);
    float* H   = (float*)(ws + 800000);
    float* A   = (float*)(ws + 800000 + (size_t)N_NODES * 64 * 4);
    float* out = (float*)d_out;

    const int EBLK = (N_EDGES + 255) / 256;  // 6250, exact

    // degree + inverse
    hipMemsetAsync(cnt, 0, N_NODES * sizeof(int), stream);
    degree_kernel<<<2048, 256, 0, stream>>>(dst, cnt, N_EDGES);
    inv_kernel<<<(N_NODES + 255) / 256, 256, 0, stream>>>(cnt, inv, N_NODES);

    // ---- layer 1: IN=6, D=64 ----
    hipMemsetAsync(A, 0, (size_t)N_NODES * 64 * 4, stream);
    edge_mlp<6, 64><<<EBLK, 256, 0, stream>>>(x, ea, src, dst, W1a, b1a, W1b, b1b, A, N_EDGES);
    node_finish<64, true><<<(N_NODES * 64 / 4 + 255) / 256, 256, 0, stream>>>(A, inv, H, N_NODES);

    // ---- layer 2: IN=64, D=64 ----
    hipMemsetAsync(A, 0, (size_t)N_NODES * 64 * 4, stream);
    edge_mlp<64, 64><<<EBLK, 256, 0, stream>>>(H, ea, src, dst, W2a, b2a, W2b, b2b, A, N_EDGES);
    node_finish<64, true><<<(N_NODES * 64 / 4 + 255) / 256, 256, 0, stream>>>(A, inv, H, N_NODES);

    // ---- layer 3: IN=64, D=32 ----
    hipMemsetAsync(A, 0, (size_t)N_NODES * 32 * 4, stream);
    edge_mlp<64, 32><<<EBLK, 256, 0, stream>>>(H, ea, src, dst, W3a, b3a, W3b, b3b, A, N_EDGES);
    node_finish<32, false><<<(N_NODES * 32 / 4 + 255) / 256, 256, 0, stream>>>(A, inv, out, N_NODES);
}

// Round 3
// 1053.774 us; speedup vs baseline: 2.7194x; 1.2129x over previous
//
#include <hip/hip_runtime.h>

#define N_NODES 100000
#define N_EDGES 1600000

// ---------------- degree / inverse ----------------
__global__ __launch_bounds__(256) void degree_kernel(const int* __restrict__ dst,
                                                     int* __restrict__ cnt, int E) {
    int i = blockIdx.x * blockDim.x + threadIdx.x;
    int stride = gridDim.x * blockDim.x;
    for (; i < E; i += stride) atomicAdd(&cnt[dst[i]], 1);
}

// inv[n] = 1/cnt (0 if cnt==0, so the commuted bias can be masked)
__global__ __launch_bounds__(256) void inv_kernel(const int* __restrict__ cnt,
                                                  float* __restrict__ inv, int N) {
    int i = blockIdx.x * blockDim.x + threadIdx.x;
    if (i < N) inv[i] = (cnt[i] > 0) ? (1.0f / (float)cnt[i]) : 0.0f;
}

// ---------------- node GEMM: out[n,:] = act( (in[n,:] * s) @ W + b * bs ) ----
// Thread-per-node; weights via wave-uniform s_load; v[IN] in registers.
// SCALE: s = inv[n], bias masked by (inv!=0)  [mean + commuted bias]
// else : s = 1, bias always applied            [pre-relu edge bias]
// NOTE: in_/out_ intentionally NOT __restrict__ — C-layers run in-place.
template <int IN, int OUT, bool RELU, bool SCALE>
__global__ __launch_bounds__(256) void node_gemm(
    const float* in_, const float* __restrict__ W, const float* __restrict__ bias,
    const float* __restrict__ inv, float* out_, int N) {
    int n = blockIdx.x * blockDim.x + threadIdx.x;
    if (n >= N) return;
    const float* row = in_ + (size_t)n * IN;
    float v[IN];
    if constexpr ((IN & 3) == 0) {
#pragma unroll
        for (int q = 0; q < IN / 4; ++q) {
            float4 t = ((const float4*)row)[q];
            v[4 * q + 0] = t.x; v[4 * q + 1] = t.y;
            v[4 * q + 2] = t.z; v[4 * q + 3] = t.w;
        }
    } else {
#pragma unroll
        for (int k = 0; k < IN; ++k) v[k] = row[k];
    }
    float bs = 1.0f;
    if constexpr (SCALE) {
        const float s = inv[n];
        bs = (s != 0.0f) ? 1.0f : 0.0f;
#pragma unroll
        for (int k = 0; k < IN; ++k) v[k] *= s;
    }
    float* orow = out_ + (size_t)n * OUT;
    for (int g = 0; g < OUT / 4; ++g) {   // rolled: weights via uniform s_load
        float a0 = bias[4 * g + 0] * bs, a1 = bias[4 * g + 1] * bs;
        float a2 = bias[4 * g + 2] * bs, a3 = bias[4 * g + 3] * bs;
#pragma unroll
        for (int k = 0; k < IN; ++k) {
            const float m = v[k];
            const float* w = &W[k * OUT + 4 * g];
            a0 = fmaf(m, w[0], a0);
            a1 = fmaf(m, w[1], a1);
            a2 = fmaf(m, w[2], a2);
            a3 = fmaf(m, w[3], a3);
        }
        if (RELU) {
            a0 = fmaxf(a0, 0.f); a1 = fmaxf(a1, 0.f);
            a2 = fmaxf(a2, 0.f); a3 = fmaxf(a3, 0.f);
        }
        ((float4*)orow)[g] = make_float4(a0, a1, a2, a3);
    }
}

// ---------------- edge scatter: acc[dst] += relu(P[src] + ea @ We) -----------
// Lane = output column (D=64: 1 edge/step, D=32: 2 edges/step). Per edge:
// one coalesced 256B gather of P row, 3 FMAs, one coalesced 256B-row atomic.
template <int D>
__global__ __launch_bounds__(256) void edge_scatter(
    const float* __restrict__ P,   // [N,D]  (x@Wa_x + ba)
    const float* __restrict__ ea,  // [E,3]
    const float* __restrict__ We,  // [3,D]  (= Wa rows IN_D..IN_D+2)
    const int* __restrict__ src, const int* __restrict__ dst,
    float* __restrict__ acc, int E) {
    constexpr int EPS = 64 / D;  // edges per wave-step
    const int lane  = threadIdx.x & 63;
    const int gwave = (blockIdx.x * blockDim.x + threadIdx.x) >> 6;
    const int nwave = (gridDim.x * blockDim.x) >> 6;
    const int c   = lane % D;
    const int sub = lane / D;
    const float w0 = We[c], w1 = We[D + c], w2 = We[2 * D + c];

    int chunk = (E + nwave - 1) / nwave;
    chunk = (chunk + 4 * EPS - 1) & ~(4 * EPS - 1);
    const int begin = gwave * chunk;
    const int end   = min(begin + chunk, E);

    for (int e0 = begin; e0 < end; e0 += 4 * EPS) {
#pragma unroll
        for (int u = 0; u < 4; ++u) {
            const int e = e0 + u * EPS + sub;
            if (e < end) {
                const int s = src[e];
                const int d = dst[e];
                const float a0 = ea[(size_t)e * 3 + 0];
                const float a1 = ea[(size_t)e * 3 + 1];
                const float a2 = ea[(size_t)e * 3 + 2];
                float h = P[(size_t)s * D + c];
                h = fmaf(a2, w2, fmaf(a1, w1, fmaf(a0, w0, h)));
                h = fmaxf(h, 0.0f);
                atomicAdd(&acc[(size_t)d * D + c], h);
            }
        }
    }
}

extern "C" void kernel_launch(void* const* d_in, const int* in_sizes, int n_in,
                              void* d_out, int out_size, void* d_ws, size_t ws_size,
                              hipStream_t stream) {
    const float* x   = (const float*)d_in[0];
    const int*   ei  = (const int*)d_in[1];
    const float* ea  = (const float*)d_in[2];
    const float* W1a = (const float*)d_in[3];
    const float* b1a = (const float*)d_in[4];
    const float* W1b = (const float*)d_in[5];
    const float* b1b = (const float*)d_in[6];
    const float* W2a = (const float*)d_in[7];
    const float* b2a = (const float*)d_in[8];
    const float* W2b = (const float*)d_in[9];
    const float* b2b = (const float*)d_in[10];
    const float* W3a = (const float*)d_in[11];
    const float* b3a = (const float*)d_in[12];
    const float* W3b = (const float*)d_in[13];
    const float* b3b = (const float*)d_in[14];

    const int* src = ei;             // edge_index[0]
    const int* dst = ei + N_EDGES;   // edge_index[1]

    // workspace: cnt[N] | inv[N] | P[N*64] | B1[N*64]   (~52 MB)
    char*  ws  = (char*)d_ws;
    int*   cnt = (int*)ws;
    float* inv = (float*)(ws + 400000);
    float* P   = (float*)(ws + 800000);
    float* B1  = (float*)(ws + 800000 + (size_t)N_NODES * 64 * 4);
    float* out = (float*)d_out;

    const int NBLK = (N_NODES + 255) / 256;  // 391
    const int EBLK = 2048;                   // 8192 waves for edge kernels

    // degree + inverse (graph is shared by all 3 layers)
    hipMemsetAsync(cnt, 0, N_NODES * sizeof(int), stream);
    degree_kernel<<<2048, 256, 0, stream>>>(dst, cnt, N_EDGES);
    inv_kernel<<<NBLK, 256, 0, stream>>>(cnt, inv, N_NODES);

    // ---- layer 1 ----
    node_gemm<6, 64, false, false><<<NBLK, 256, 0, stream>>>(x, W1a, b1a, nullptr, P, N_NODES);
    hipMemsetAsync(B1, 0, (size_t)N_NODES * 64 * 4, stream);
    edge_scatter<64><<<EBLK, 256, 0, stream>>>(P, ea, W1a + 6 * 64, src, dst, B1, N_EDGES);
    node_gemm<64, 64, true, true><<<NBLK, 256, 0, stream>>>(B1, W1b, b1b, inv, B1, N_NODES);

    // ---- layer 2 ----
    node_gemm<64, 64, false, false><<<NBLK, 256, 0, stream>>>(B1, W2a, b2a, nullptr, P, N_NODES);
    hipMemsetAsync(B1, 0, (size_t)N_NODES * 64 * 4, stream);
    edge_scatter<64><<<EBLK, 256, 0, stream>>>(P, ea, W2a + 64 * 64, src, dst, B1, N_EDGES);
    node_gemm<64, 64, true, true><<<NBLK, 256, 0, stream>>>(B1, W2b, b2b, inv, B1, N_NODES);

    // ---- layer 3 (D=32) ----
    node_gemm<64, 32, false, false><<<NBLK, 256, 0, stream>>>(B1, W3a, b3a, nullptr, P, N_NODES);
    hipMemsetAsync(B1, 0, (size_t)N_NODES * 32 * 4, stream);
    edge_scatter<32><<<EBLK, 256, 0, stream>>>(P, ea, W3a + 64 * 32, src, dst, B1, N_EDGES);
    node_gemm<32, 32, false, true><<<NBLK, 256, 0, stream>>>(B1, W3b, b3b, inv, out, N_NODES);
}

// Round 4
// 625.053 us; speedup vs baseline: 4.5847x; 1.6859x over previous
//
#include <hip/hip_runtime.h>

#define N_NODES 100000
#define N_EDGES 1600000

// ---------------- degree ----------------
__global__ __launch_bounds__(256) void degree_kernel(const int* __restrict__ dst,
                                                     int* __restrict__ cnt, int E) {
    int i = blockIdx.x * blockDim.x + threadIdx.x;
    int stride = gridDim.x * blockDim.x;
    for (; i < E; i += stride) atomicAdd(&cnt[dst[i]], 1);
}

__global__ __launch_bounds__(256) void inv_kernel(const int* __restrict__ cnt,
                                                  float* __restrict__ inv, int N) {
    int i = blockIdx.x * blockDim.x + threadIdx.x;
    if (i < N) inv[i] = (cnt[i] > 0) ? (1.0f / (float)cnt[i]) : 0.0f;
}

// ---------------- hierarchical exclusive scan (cnt -> cursor) ----------------
__global__ __launch_bounds__(256) void block_sum_kernel(const int* __restrict__ cnt,
                                                        int* __restrict__ bsum, int N) {
    __shared__ int s[256];
    const int tid = threadIdx.x;
    const int i = blockIdx.x * 256 + tid;
    s[tid] = (i < N) ? cnt[i] : 0;
    __syncthreads();
#pragma unroll
    for (int d = 128; d > 0; d >>= 1) {
        if (tid < d) s[tid] += s[tid + d];
        __syncthreads();
    }
    if (tid == 0) bsum[blockIdx.x] = s[0];
}

// single block, 512 threads: in-place exclusive scan of bsum[NB], NB<=512
__global__ __launch_bounds__(512) void scan_bsum_kernel(int* __restrict__ bsum, int NB) {
    __shared__ int s[512];
    const int tid = threadIdx.x;
    const int v = (tid < NB) ? bsum[tid] : 0;
    s[tid] = v;
    __syncthreads();
    for (int d = 1; d < 512; d <<= 1) {
        const int t = (tid >= d) ? s[tid - d] : 0;
        __syncthreads();
        s[tid] += t;
        __syncthreads();
    }
    if (tid < NB) bsum[tid] = s[tid] - v;  // exclusive
}

__global__ __launch_bounds__(256) void make_cursor_kernel(const int* __restrict__ cnt,
                                                          const int* __restrict__ bsum,
                                                          int* __restrict__ cursor, int N) {
    __shared__ int s[256];
    const int tid = threadIdx.x;
    const int i = blockIdx.x * 256 + tid;
    const int v = (i < N) ? cnt[i] : 0;
    s[tid] = v;
    __syncthreads();
    for (int d = 1; d < 256; d <<= 1) {
        const int t = (tid >= d) ? s[tid - d] : 0;
        __syncthreads();
        s[tid] += t;
        __syncthreads();
    }
    if (i < N) cursor[i] = bsum[blockIdx.x] + s[tid] - v;  // global exclusive prefix
}

// ---------------- CSR scatter: sp[pos] = (src[i], i) ----------------
__global__ __launch_bounds__(256) void scatter_pack_kernel(
    const int* __restrict__ src, const int* __restrict__ dst,
    int* __restrict__ cursor, int2* __restrict__ sp, int E) {
    int i = blockIdx.x * blockDim.x + threadIdx.x;
    const int stride = gridDim.x * blockDim.x;
    for (; i < E; i += stride) {
        const int d = dst[i];
        const int pos = atomicAdd(&cursor[d], 1);
        sp[pos] = make_int2(src[i], i);
    }
}

// ---------------- CSR aggregate: B[n,c] = sum_e relu(P[src_e,c] + ea_e @ We[:,c]) ----
// Wave per node (D=64) or per pair of nodes (D=32). Lane = column.
// After scatter, cursor[n] = end of node n's range; begin = end - cnt[n].
template <int D>
__global__ __launch_bounds__(256) void aggregate_kernel(
    const float* __restrict__ P,       // [N,D]  (x@Wa_x + ba)
    const int2* __restrict__ sp,       // [E]    (src, edge_id) in CSR order
    const float* __restrict__ ea,      // [E,3]  original order
    const int* __restrict__ cursor,    // [N]    end offsets
    const int* __restrict__ cnt,       // [N]
    const float* __restrict__ We,      // [3,D]
    float* __restrict__ B, int N) {
    constexpr int NPW = 64 / D;  // nodes per wave
    const int lane = threadIdx.x & 63;
    const int gw   = (blockIdx.x * blockDim.x + threadIdx.x) >> 6;
    const int c    = lane % D;
    const int sub  = lane / D;
    const int n    = gw * NPW + sub;
    if (n >= N) return;

    const float w0 = We[c], w1 = We[D + c], w2 = We[2 * D + c];
    const int end   = cursor[n];
    const int count = cnt[n];
    int j = end - count;

    float s = 0.0f;
    for (; j + 2 <= end; j += 2) {
        const int2 e0 = sp[j];
        const int2 e1 = sp[j + 1];
        const float p0 = P[(size_t)e0.x * D + c];
        const float p1 = P[(size_t)e1.x * D + c];
        const float a00 = ea[(size_t)e0.y * 3 + 0];
        const float a01 = ea[(size_t)e0.y * 3 + 1];
        const float a02 = ea[(size_t)e0.y * 3 + 2];
        const float a10 = ea[(size_t)e1.y * 3 + 0];
        const float a11 = ea[(size_t)e1.y * 3 + 1];
        const float a12 = ea[(size_t)e1.y * 3 + 2];
        const float h0 = fmaf(a02, w2, fmaf(a01, w1, fmaf(a00, w0, p0)));
        const float h1 = fmaf(a12, w2, fmaf(a11, w1, fmaf(a10, w0, p1)));
        s += fmaxf(h0, 0.0f);
        s += fmaxf(h1, 0.0f);
    }
    if (j < end) {
        const int2 e0 = sp[j];
        const float p0 = P[(size_t)e0.x * D + c];
        const float a00 = ea[(size_t)e0.y * 3 + 0];
        const float a01 = ea[(size_t)e0.y * 3 + 1];
        const float a02 = ea[(size_t)e0.y * 3 + 2];
        const float h0 = fmaf(a02, w2, fmaf(a01, w1, fmaf(a00, w0, p0)));
        s += fmaxf(h0, 0.0f);
    }
    B[(size_t)n * D + c] = s;
}

// ---------------- node GEMM (unchanged from round 3) ----------------
template <int IN, int OUT, bool RELU, bool SCALE>
__global__ __launch_bounds__(256) void node_gemm(
    const float* in_, const float* __restrict__ W, const float* __restrict__ bias,
    const float* __restrict__ inv, float* out_, int N) {
    int n = blockIdx.x * blockDim.x + threadIdx.x;
    if (n >= N) return;
    const float* row = in_ + (size_t)n * IN;
    float v[IN];
    if constexpr ((IN & 3) == 0) {
#pragma unroll
        for (int q = 0; q < IN / 4; ++q) {
            float4 t = ((const float4*)row)[q];
            v[4 * q + 0] = t.x; v[4 * q + 1] = t.y;
            v[4 * q + 2] = t.z; v[4 * q + 3] = t.w;
        }
    } else {
#pragma unroll
        for (int k = 0; k < IN; ++k) v[k] = row[k];
    }
    float bs = 1.0f;
    if constexpr (SCALE) {
        const float s = inv[n];
        bs = (s != 0.0f) ? 1.0f : 0.0f;
#pragma unroll
        for (int k = 0; k < IN; ++k) v[k] *= s;
    }
    float* orow = out_ + (size_t)n * OUT;
    for (int g = 0; g < OUT / 4; ++g) {   // rolled: weights via uniform s_load
        float a0 = bias[4 * g + 0] * bs, a1 = bias[4 * g + 1] * bs;
        float a2 = bias[4 * g + 2] * bs, a3 = bias[4 * g + 3] * bs;
#pragma unroll
        for (int k = 0; k < IN; ++k) {
            const float m = v[k];
            const float* w = &W[k * OUT + 4 * g];
            a0 = fmaf(m, w[0], a0);
            a1 = fmaf(m, w[1], a1);
            a2 = fmaf(m, w[2], a2);
            a3 = fmaf(m, w[3], a3);
        }
        if (RELU) {
            a0 = fmaxf(a0, 0.f); a1 = fmaxf(a1, 0.f);
            a2 = fmaxf(a2, 0.f); a3 = fmaxf(a3, 0.f);
        }
        ((float4*)orow)[g] = make_float4(a0, a1, a2, a3);
    }
}

// ---------------- fallback: atomic edge scatter (round-3 path) ----------------
template <int D>
__global__ __launch_bounds__(256) void edge_scatter(
    const float* __restrict__ P, const float* __restrict__ ea,
    const float* __restrict__ We,
    const int* __restrict__ src, const int* __restrict__ dst,
    float* __restrict__ acc, int E) {
    constexpr int EPS = 64 / D;
    const int lane  = threadIdx.x & 63;
    const int gwave = (blockIdx.x * blockDim.x + threadIdx.x) >> 6;
    const int nwave = (gridDim.x * blockDim.x) >> 6;
    const int c   = lane % D;
    const int sub = lane / D;
    const float w0 = We[c], w1 = We[D + c], w2 = We[2 * D + c];
    int chunk = (E + nwave - 1) / nwave;
    chunk = (chunk + 4 * EPS - 1) & ~(4 * EPS - 1);
    const int begin = gwave * chunk;
    const int end   = min(begin + chunk, E);
    for (int e0 = begin; e0 < end; e0 += 4 * EPS) {
#pragma unroll
        for (int u = 0; u < 4; ++u) {
            const int e = e0 + u * EPS + sub;
            if (e < end) {
                const int s = src[e];
                const int d = dst[e];
                const float a0 = ea[(size_t)e * 3 + 0];
                const float a1 = ea[(size_t)e * 3 + 1];
                const float a2 = ea[(size_t)e * 3 + 2];
                float h = P[(size_t)s * D + c];
                h = fmaf(a2, w2, fmaf(a1, w1, fmaf(a0, w0, h)));
                h = fmaxf(h, 0.0f);
                atomicAdd(&acc[(size_t)d * D + c], h);
            }
        }
    }
}

extern "C" void kernel_launch(void* const* d_in, const int* in_sizes, int n_in,
                              void* d_out, int out_size, void* d_ws, size_t ws_size,
                              hipStream_t stream) {
    const float* x   = (const float*)d_in[0];
    const int*   ei  = (const int*)d_in[1];
    const float* ea  = (const float*)d_in[2];
    const float* W1a = (const float*)d_in[3];
    const float* b1a = (const float*)d_in[4];
    const float* W1b = (const float*)d_in[5];
    const float* b1b = (const float*)d_in[6];
    const float* W2a = (const float*)d_in[7];
    const float* b2a = (const float*)d_in[8];
    const float* W2b = (const float*)d_in[9];
    const float* b2b = (const float*)d_in[10];
    const float* W3a = (const float*)d_in[11];
    const float* b3a = (const float*)d_in[12];
    const float* W3b = (const float*)d_in[13];
    const float* b3b = (const float*)d_in[14];

    const int* src = ei;
    const int* dst = ei + N_EDGES;
    float* out = (float*)d_out;

    const int NBLK = (N_NODES + 255) / 256;  // 391

    if (ws_size >= (size_t)70 * 1024 * 1024) {
        // ---- CSR path ----
        // layout (byte offsets): cnt 0 | inv 0x80000 | bsum 0x100000 |
        // cursor 0x110000 | sp 0x200000 (12.8MB) | P 0x1000000 (25.6MB) |
        // B1 0x2A00000 (25.6MB)  -> ends ~67.6MB
        char* ws = (char*)d_ws;
        int*   cnt    = (int*)(ws);
        float* inv    = (float*)(ws + 0x80000);
        int*   bsum   = (int*)(ws + 0x100000);
        int*   cursor = (int*)(ws + 0x110000);
        int2*  sp     = (int2*)(ws + 0x200000);
        float* P      = (float*)(ws + 0x1000000);
        float* B1     = (float*)(ws + 0x2A00000);

        // graph preprocessing (once, reused by all 3 layers)
        hipMemsetAsync(cnt, 0, N_NODES * sizeof(int), stream);
        degree_kernel<<<2048, 256, 0, stream>>>(dst, cnt, N_EDGES);
        inv_kernel<<<NBLK, 256, 0, stream>>>(cnt, inv, N_NODES);
        block_sum_kernel<<<NBLK, 256, 0, stream>>>(cnt, bsum, N_NODES);
        scan_bsum_kernel<<<1, 512, 0, stream>>>(bsum, NBLK);
        make_cursor_kernel<<<NBLK, 256, 0, stream>>>(cnt, bsum, cursor, N_NODES);
        scatter_pack_kernel<<<2048, 256, 0, stream>>>(src, dst, cursor, sp, N_EDGES);
        // now cursor[n] = end offset of node n

        const int AB64 = (N_NODES + 3) / 4;        // 4 waves/block, 1 node/wave
        const int AB32 = (N_NODES / 2 + 3) / 4;    // 2 nodes/wave

        // ---- layer 1 ----
        node_gemm<6, 64, false, false><<<NBLK, 256, 0, stream>>>(x, W1a, b1a, nullptr, P, N_NODES);
        aggregate_kernel<64><<<AB64, 256, 0, stream>>>(P, sp, ea, cursor, cnt, W1a + 6 * 64, B1, N_NODES);
        node_gemm<64, 64, true, true><<<NBLK, 256, 0, stream>>>(B1, W1b, b1b, inv, B1, N_NODES);

        // ---- layer 2 ----
        node_gemm<64, 64, false, false><<<NBLK, 256, 0, stream>>>(B1, W2a, b2a, nullptr, P, N_NODES);
        aggregate_kernel<64><<<AB64, 256, 0, stream>>>(P, sp, ea, cursor, cnt, W2a + 64 * 64, B1, N_NODES);
        node_gemm<64, 64, true, true><<<NBLK, 256, 0, stream>>>(B1, W2b, b2b, inv, B1, N_NODES);

        // ---- layer 3 (D=32) ----
        node_gemm<64, 32, false, false><<<NBLK, 256, 0, stream>>>(B1, W3a, b3a, nullptr, P, N_NODES);
        aggregate_kernel<32><<<AB32, 256, 0, stream>>>(P, sp, ea, cursor, cnt, W3a + 64 * 32, B1, N_NODES);
        node_gemm<32, 32, false, true><<<NBLK, 256, 0, stream>>>(B1, W3b, b3b, inv, out, N_NODES);
    } else {
        // ---- fallback: round-3 atomic path (needs ~52MB) ----
        char* ws = (char*)d_ws;
        int*   cnt = (int*)ws;
        float* inv = (float*)(ws + 400000);
        float* P   = (float*)(ws + 800000);
        float* B1  = (float*)(ws + 800000 + (size_t)N_NODES * 64 * 4);

        hipMemsetAsync(cnt, 0, N_NODES * sizeof(int), stream);
        degree_kernel<<<2048, 256, 0, stream>>>(dst, cnt, N_EDGES);
        inv_kernel<<<NBLK, 256, 0, stream>>>(cnt, inv, N_NODES);

        node_gemm<6, 64, false, false><<<NBLK, 256, 0, stream>>>(x, W1a, b1a, nullptr, P, N_NODES);
        hipMemsetAsync(B1, 0, (size_t)N_NODES * 64 * 4, stream);
        edge_scatter<64><<<2048, 256, 0, stream>>>(P, ea, W1a + 6 * 64, src, dst, B1, N_EDGES);
        node_gemm<64, 64, true, true><<<NBLK, 256, 0, stream>>>(B1, W1b, b1b, inv, B1, N_NODES);

        node_gemm<64, 64, false, false><<<NBLK, 256, 0, stream>>>(B1, W2a, b2a, nullptr, P, N_NODES);
        hipMemsetAsync(B1, 0, (size_t)N_NODES * 64 * 4, stream);
        edge_scatter<64><<<2048, 256, 0, stream>>>(P, ea, W2a + 64 * 64, src, dst, B1, N_EDGES);
        node_gemm<64, 64, true, true><<<NBLK, 256, 0, stream>>>(B1, W2b, b2b, inv, B1, N_NODES);

        node_gemm<64, 32, false, false><<<NBLK, 256, 0, stream>>>(B1, W3a, b3a, nullptr, P, N_NODES);
        hipMemsetAsync(B1, 0, (size_t)N_NODES * 32 * 4, stream);
        edge_scatter<32><<<2048, 256, 0, stream>>>(P, ea, W3a + 64 * 32, src, dst, B1, N_EDGES);
        node_gemm<32, 32, false, true><<<NBLK, 256, 0, stream>>>(B1, W3b, b3b, inv, out, N_NODES);
    }
}

// Round 5
// 615.739 us; speedup vs baseline: 4.6540x; 1.0151x over previous
//
#include <hip/hip_runtime.h>

#define N_NODES 100000
#define N_EDGES 1600000

// ---------------- degree ----------------
__global__ __launch_bounds__(256) void degree_kernel(const int* __restrict__ dst,
                                                     int* __restrict__ cnt, int E) {
    int i = blockIdx.x * blockDim.x + threadIdx.x;
    int stride = gridDim.x * blockDim.x;
    for (; i < E; i += stride) atomicAdd(&cnt[dst[i]], 1);
}

__global__ __launch_bounds__(256) void inv_kernel(const int* __restrict__ cnt,
                                                  float* __restrict__ inv, int N) {
    int i = blockIdx.x * blockDim.x + threadIdx.x;
    if (i < N) inv[i] = (cnt[i] > 0) ? (1.0f / (float)cnt[i]) : 0.0f;
}

// ---------------- hierarchical exclusive scan (cnt -> cursor) ----------------
__global__ __launch_bounds__(256) void block_sum_kernel(const int* __restrict__ cnt,
                                                        int* __restrict__ bsum, int N) {
    __shared__ int s[256];
    const int tid = threadIdx.x;
    const int i = blockIdx.x * 256 + tid;
    s[tid] = (i < N) ? cnt[i] : 0;
    __syncthreads();
#pragma unroll
    for (int d = 128; d > 0; d >>= 1) {
        if (tid < d) s[tid] += s[tid + d];
        __syncthreads();
    }
    if (tid == 0) bsum[blockIdx.x] = s[0];
}

__global__ __launch_bounds__(512) void scan_bsum_kernel(int* __restrict__ bsum, int NB) {
    __shared__ int s[512];
    const int tid = threadIdx.x;
    const int v = (tid < NB) ? bsum[tid] : 0;
    s[tid] = v;
    __syncthreads();
    for (int d = 1; d < 512; d <<= 1) {
        const int t = (tid >= d) ? s[tid - d] : 0;
        __syncthreads();
        s[tid] += t;
        __syncthreads();
    }
    if (tid < NB) bsum[tid] = s[tid] - v;  // exclusive
}

__global__ __launch_bounds__(256) void make_cursor_kernel(const int* __restrict__ cnt,
                                                          const int* __restrict__ bsum,
                                                          int* __restrict__ cursor, int N) {
    __shared__ int s[256];
    const int tid = threadIdx.x;
    const int i = blockIdx.x * 256 + tid;
    const int v = (i < N) ? cnt[i] : 0;
    s[tid] = v;
    __syncthreads();
    for (int d = 1; d < 256; d <<= 1) {
        const int t = (tid >= d) ? s[tid - d] : 0;
        __syncthreads();
        s[tid] += t;
        __syncthreads();
    }
    if (i < N) cursor[i] = bsum[blockIdx.x] + s[tid] - v;
}

// ---------------- XCD-partitioned CSR scatter with float4 payload ------------
// Blocks with blockIdx%8==r process only dst in range r. All CSR lines of a
// node are then written from (heuristically) one XCD -> its L2 merges the
// partial-line writes before writeback. Payload carries src + edge_attr so
// aggregation reads ea sequentially in CSR order.
__global__ __launch_bounds__(256) void scatter_pack_kernel(
    const int* __restrict__ src, const int* __restrict__ dst,
    const float* __restrict__ ea,
    int* __restrict__ cursor, float4* __restrict__ spf, int E) {
    const int range = blockIdx.x & 7;
    const int lo = range * (N_NODES / 8);
    const int hi = lo + (N_NODES / 8);
    int i = (blockIdx.x >> 3) * blockDim.x + threadIdx.x;
    const int stride = (gridDim.x >> 3) * blockDim.x;
    for (; i < E; i += stride) {
        const int d = dst[i];
        if (d >= lo && d < hi) {
            const int pos = atomicAdd(&cursor[d], 1);
            spf[pos] = make_float4(__int_as_float(src[i]),
                                   ea[3 * (size_t)i + 0],
                                   ea[3 * (size_t)i + 1],
                                   ea[3 * (size_t)i + 2]);
        }
    }
}

// ---------------- fused layer 1: x-gather agg + Wb GEMM + next Wa GEMM -------
// Wave per node, lane = column. Per edge: project x[src] (6-wide) with per-lane
// W1a column regs, add ea@We, relu, accumulate. Epilogue: two 64x64 GEMMs via
// wave-local LDS transpose (wave-synchronous, no __syncthreads).
__global__ __launch_bounds__(256) void fused_l1(
    const float* __restrict__ x,     // [N,6]
    const float4* __restrict__ spf,
    const int* __restrict__ cursor, const int* __restrict__ cnt,
    const float* __restrict__ inv,
    const float* __restrict__ W1a,   // [9,64]
    const float* __restrict__ b1a,
    const float* __restrict__ W1b,   // [64,64]
    const float* __restrict__ b1b,
    const float* __restrict__ W2a,   // [67,64] rows 0..63 used
    const float* __restrict__ b2a,
    float* __restrict__ P2, int N) {
    const int lane = threadIdx.x & 63;
    const int w    = threadIdx.x >> 6;
    const int n    = blockIdx.x * 4 + w;
    const int c    = lane;

    __shared__ __align__(16) float lrow[4][64];

    float wx[6];
#pragma unroll
    for (int k = 0; k < 6; ++k) wx[k] = W1a[k * 64 + c];
    const float we0 = W1a[6 * 64 + c], we1 = W1a[7 * 64 + c], we2 = W1a[8 * 64 + c];
    const float pb  = b1a[c];

    const int end   = cursor[n];
    const int count = cnt[n];
    int j = end - count;
    const float s_inv = inv[n];
    const float mask  = (s_inv != 0.0f) ? 1.0f : 0.0f;

    float sum = 0.0f;
    for (; j + 2 <= end; j += 2) {
        const float4 f0 = spf[j];
        const float4 f1 = spf[j + 1];
        const float* xr0 = x + (size_t)__float_as_int(f0.x) * 6;
        const float* xr1 = x + (size_t)__float_as_int(f1.x) * 6;
        const float2 xa0 = *(const float2*)(xr0);
        const float2 xb0 = *(const float2*)(xr0 + 2);
        const float2 xc0 = *(const float2*)(xr0 + 4);
        const float2 xa1 = *(const float2*)(xr1);
        const float2 xb1 = *(const float2*)(xr1 + 2);
        const float2 xc1 = *(const float2*)(xr1 + 4);
        float h0 = pb, h1 = pb;
        h0 = fmaf(xa0.x, wx[0], h0); h1 = fmaf(xa1.x, wx[0], h1);
        h0 = fmaf(xa0.y, wx[1], h0); h1 = fmaf(xa1.y, wx[1], h1);
        h0 = fmaf(xb0.x, wx[2], h0); h1 = fmaf(xb1.x, wx[2], h1);
        h0 = fmaf(xb0.y, wx[3], h0); h1 = fmaf(xb1.y, wx[3], h1);
        h0 = fmaf(xc0.x, wx[4], h0); h1 = fmaf(xc1.x, wx[4], h1);
        h0 = fmaf(xc0.y, wx[5], h0); h1 = fmaf(xc1.y, wx[5], h1);
        h0 = fmaf(f0.y, we0, h0);    h1 = fmaf(f1.y, we0, h1);
        h0 = fmaf(f0.z, we1, h0);    h1 = fmaf(f1.z, we1, h1);
        h0 = fmaf(f0.w, we2, h0);    h1 = fmaf(f1.w, we2, h1);
        sum += fmaxf(h0, 0.0f) + fmaxf(h1, 0.0f);
    }
    if (j < end) {
        const float4 f0 = spf[j];
        const float* xr0 = x + (size_t)__float_as_int(f0.x) * 6;
        const float2 xa0 = *(const float2*)(xr0);
        const float2 xb0 = *(const float2*)(xr0 + 2);
        const float2 xc0 = *(const float2*)(xr0 + 4);
        float h0 = pb;
        h0 = fmaf(xa0.x, wx[0], h0); h0 = fmaf(xa0.y, wx[1], h0);
        h0 = fmaf(xb0.x, wx[2], h0); h0 = fmaf(xb0.y, wx[3], h0);
        h0 = fmaf(xc0.x, wx[4], h0); h0 = fmaf(xc0.y, wx[5], h0);
        h0 = fmaf(f0.y, we0, h0); h0 = fmaf(f0.z, we1, h0); h0 = fmaf(f0.w, we2, h0);
        sum += fmaxf(h0, 0.0f);
    }

    // epilogue: t = sum*inv; mid = relu(t@W1b + b1b*mask); out = mid@W2a + b2a
    const float t = sum * s_inv;
    lrow[w][lane] = t;
    __builtin_amdgcn_wave_barrier();
    float m = b1b[c] * mask;
#pragma unroll
    for (int q = 0; q < 16; ++q) {
        const float4 r = *(const float4*)&lrow[w][4 * q];
        m = fmaf(r.x, W1b[(4 * q + 0) * 64 + c], m);
        m = fmaf(r.y, W1b[(4 * q + 1) * 64 + c], m);
        m = fmaf(r.z, W1b[(4 * q + 2) * 64 + c], m);
        m = fmaf(r.w, W1b[(4 * q + 3) * 64 + c], m);
    }
    m = fmaxf(m, 0.0f);
    __builtin_amdgcn_wave_barrier();
    lrow[w][lane] = m;
    __builtin_amdgcn_wave_barrier();
    float o = b2a[c];
#pragma unroll
    for (int q = 0; q < 16; ++q) {
        const float4 r = *(const float4*)&lrow[w][4 * q];
        o = fmaf(r.x, W2a[(4 * q + 0) * 64 + c], o);
        o = fmaf(r.y, W2a[(4 * q + 1) * 64 + c], o);
        o = fmaf(r.z, W2a[(4 * q + 2) * 64 + c], o);
        o = fmaf(r.w, W2a[(4 * q + 3) * 64 + c], o);
    }
    P2[(size_t)n * 64 + c] = o;
}

// ---------------- fused mid/last layer: P-gather agg + GEMM epilogue ---------
// DIN=64: 1 node/wave. DIN=32: 2 nodes/wave. LAST: single GEMM (Wb), no relu.
template <int DIN, int DNEXT, bool LAST>
__global__ __launch_bounds__(256) void fused_agg(
    const float* __restrict__ P,     // [N,DIN]
    const float4* __restrict__ spf,
    const int* __restrict__ cursor, const int* __restrict__ cnt,
    const float* __restrict__ inv,
    const float* __restrict__ We,    // [3,DIN]
    const float* __restrict__ Wb,    // [DIN,DIN]
    const float* __restrict__ bb,
    const float* __restrict__ Wn,    // [DIN,DNEXT] (unused if LAST)
    const float* __restrict__ bn,
    float* __restrict__ Pout, int N) {
    constexpr int NPW = 64 / DIN;
    const int lane = threadIdx.x & 63;
    const int w    = threadIdx.x >> 6;
    const int c    = lane % DIN;
    const int sub  = lane / DIN;
    const int n    = (blockIdx.x * 4 + w) * NPW + sub;

    __shared__ __align__(16) float lrow[4][64];

    const float we0 = We[c], we1 = We[DIN + c], we2 = We[2 * DIN + c];
    const int end   = cursor[n];
    const int count = cnt[n];
    int j = end - count;
    const float s_inv = inv[n];
    const float mask  = (s_inv != 0.0f) ? 1.0f : 0.0f;

    float sum = 0.0f;
    for (; j + 2 <= end; j += 2) {
        const float4 f0 = spf[j];
        const float4 f1 = spf[j + 1];
        const float p0 = P[(size_t)__float_as_int(f0.x) * DIN + c];
        const float p1 = P[(size_t)__float_as_int(f1.x) * DIN + c];
        const float h0 = fmaf(f0.w, we2, fmaf(f0.z, we1, fmaf(f0.y, we0, p0)));
        const float h1 = fmaf(f1.w, we2, fmaf(f1.z, we1, fmaf(f1.y, we0, p1)));
        sum += fmaxf(h0, 0.0f) + fmaxf(h1, 0.0f);
    }
    if (j < end) {
        const float4 f0 = spf[j];
        const float p0 = P[(size_t)__float_as_int(f0.x) * DIN + c];
        const float h0 = fmaf(f0.w, we2, fmaf(f0.z, we1, fmaf(f0.y, we0, p0)));
        sum += fmaxf(h0, 0.0f);
    }

    const float t = sum * s_inv;
    lrow[w][lane] = t;
    __builtin_amdgcn_wave_barrier();
    float m = bb[c] * mask;
#pragma unroll
    for (int q = 0; q < DIN / 4; ++q) {
        const float4 r = *(const float4*)&lrow[w][sub * DIN + 4 * q];
        m = fmaf(r.x, Wb[(4 * q + 0) * DIN + c], m);
        m = fmaf(r.y, Wb[(4 * q + 1) * DIN + c], m);
        m = fmaf(r.z, Wb[(4 * q + 2) * DIN + c], m);
        m = fmaf(r.w, Wb[(4 * q + 3) * DIN + c], m);
    }
    if constexpr (LAST) {
        Pout[(size_t)n * DIN + c] = m;
    } else {
        m = fmaxf(m, 0.0f);
        __builtin_amdgcn_wave_barrier();
        lrow[w][lane] = m;
        __builtin_amdgcn_wave_barrier();
        const int c2 = lane % DNEXT;
        float o = bn[c2];
#pragma unroll
        for (int q = 0; q < DIN / 4; ++q) {
            const float4 r = *(const float4*)&lrow[w][4 * q];
            o = fmaf(r.x, Wn[(4 * q + 0) * DNEXT + c2], o);
            o = fmaf(r.y, Wn[(4 * q + 1) * DNEXT + c2], o);
            o = fmaf(r.z, Wn[(4 * q + 2) * DNEXT + c2], o);
            o = fmaf(r.w, Wn[(4 * q + 3) * DNEXT + c2], o);
        }
        if (lane < DNEXT) Pout[(size_t)n * DNEXT + lane] = o;
    }
}

extern "C" void kernel_launch(void* const* d_in, const int* in_sizes, int n_in,
                              void* d_out, int out_size, void* d_ws, size_t ws_size,
                              hipStream_t stream) {
    const float* x   = (const float*)d_in[0];
    const int*   ei  = (const int*)d_in[1];
    const float* ea  = (const float*)d_in[2];
    const float* W1a = (const float*)d_in[3];
    const float* b1a = (const float*)d_in[4];
    const float* W1b = (const float*)d_in[5];
    const float* b1b = (const float*)d_in[6];
    const float* W2a = (const float*)d_in[7];
    const float* b2a = (const float*)d_in[8];
    const float* W2b = (const float*)d_in[9];
    const float* b2b = (const float*)d_in[10];
    const float* W3a = (const float*)d_in[11];
    const float* b3a = (const float*)d_in[12];
    const float* W3b = (const float*)d_in[13];
    const float* b3b = (const float*)d_in[14];

    const int* src = ei;
    const int* dst = ei + N_EDGES;
    float* out = (float*)d_out;

    // workspace (byte offsets), total ~68.4 MB:
    // cnt 0x0 | inv 0x80000 | bsum 0x100000 | cursor 0x110000 |
    // spf 0x200000 (25.6MB) | PA 0x1C00000 (25.6MB, [N,64]) | PB 0x3500000 (12.8MB, [N,32])
    char* ws = (char*)d_ws;
    int*    cnt    = (int*)(ws);
    float*  inv    = (float*)(ws + 0x80000);
    int*    bsum   = (int*)(ws + 0x100000);
    int*    cursor = (int*)(ws + 0x110000);
    float4* spf    = (float4*)(ws + 0x200000);
    float*  PA     = (float*)(ws + 0x1C00000);
    float*  PB     = (float*)(ws + 0x3500000);

    const int NBLK = (N_NODES + 255) / 256;  // 391

    // graph preprocessing (shared by all 3 layers)
    hipMemsetAsync(cnt, 0, N_NODES * sizeof(int), stream);
    degree_kernel<<<2048, 256, 0, stream>>>(dst, cnt, N_EDGES);
    inv_kernel<<<NBLK, 256, 0, stream>>>(cnt, inv, N_NODES);
    block_sum_kernel<<<NBLK, 256, 0, stream>>>(cnt, bsum, N_NODES);
    scan_bsum_kernel<<<1, 512, 0, stream>>>(bsum, NBLK);
    make_cursor_kernel<<<NBLK, 256, 0, stream>>>(cnt, bsum, cursor, N_NODES);
    scatter_pack_kernel<<<2048, 256, 0, stream>>>(src, dst, ea, cursor, spf, N_EDGES);
    // cursor[n] = end offset of node n's CSR range

    // layer 1 (x-gather, 6->64, epilogue -> P2 = PA)
    fused_l1<<<N_NODES / 4, 256, 0, stream>>>(x, spf, cursor, cnt, inv,
                                              W1a, b1a, W1b, b1b, W2a, b2a, PA, N_NODES);
    // layer 2 (64-gather, epilogue W2b then W3a -> P3 = PB, [N,32])
    fused_agg<64, 32, false><<<N_NODES / 4, 256, 0, stream>>>(
        PA, spf, cursor, cnt, inv, W2a + 64 * 64, W2b, b2b, W3a, b3a, PB, N_NODES);
    // layer 3 (32-gather, final W3b -> out)
    fused_agg<32, 32, true><<<N_NODES / 8, 256, 0, stream>>>(
        PB, spf, cursor, cnt, inv, W3a + 64 * 32, W3b, b3b, nullptr, nullptr, out, N_NODES);
}

// Round 6
// 583.242 us; speedup vs baseline: 4.9133x; 1.0557x over previous
//
#include <hip/hip_runtime.h>

#define N_NODES 100000
#define N_EDGES 1600000

// ---------------- degree ----------------
__global__ __launch_bounds__(256) void degree_kernel(const int* __restrict__ dst,
                                                     int* __restrict__ cnt, int E) {
    int i = blockIdx.x * blockDim.x + threadIdx.x;
    int stride = gridDim.x * blockDim.x;
    for (; i < E; i += stride) atomicAdd(&cnt[dst[i]], 1);
}

__global__ __launch_bounds__(256) void inv_kernel(const int* __restrict__ cnt,
                                                  float* __restrict__ inv, int N) {
    int i = blockIdx.x * blockDim.x + threadIdx.x;
    if (i < N) inv[i] = (cnt[i] > 0) ? (1.0f / (float)cnt[i]) : 0.0f;
}

// ---------------- hierarchical exclusive scan (cnt -> cursor) ----------------
__global__ __launch_bounds__(256) void block_sum_kernel(const int* __restrict__ cnt,
                                                        int* __restrict__ bsum, int N) {
    __shared__ int s[256];
    const int tid = threadIdx.x;
    const int i = blockIdx.x * 256 + tid;
    s[tid] = (i < N) ? cnt[i] : 0;
    __syncthreads();
#pragma unroll
    for (int d = 128; d > 0; d >>= 1) {
        if (tid < d) s[tid] += s[tid + d];
        __syncthreads();
    }
    if (tid == 0) bsum[blockIdx.x] = s[0];
}

__global__ __launch_bounds__(512) void scan_bsum_kernel(int* __restrict__ bsum, int NB) {
    __shared__ int s[512];
    const int tid = threadIdx.x;
    const int v = (tid < NB) ? bsum[tid] : 0;
    s[tid] = v;
    __syncthreads();
    for (int d = 1; d < 512; d <<= 1) {
        const int t = (tid >= d) ? s[tid - d] : 0;
        __syncthreads();
        s[tid] += t;
        __syncthreads();
    }
    if (tid < NB) bsum[tid] = s[tid] - v;  // exclusive
}

__global__ __launch_bounds__(256) void make_cursor_kernel(const int* __restrict__ cnt,
                                                          const int* __restrict__ bsum,
                                                          int* __restrict__ cursor, int N) {
    __shared__ int s[256];
    const int tid = threadIdx.x;
    const int i = blockIdx.x * 256 + tid;
    const int v = (i < N) ? cnt[i] : 0;
    s[tid] = v;
    __syncthreads();
    for (int d = 1; d < 256; d <<= 1) {
        const int t = (tid >= d) ? s[tid - d] : 0;
        __syncthreads();
        s[tid] += t;
        __syncthreads();
    }
    if (i < N) cursor[i] = bsum[blockIdx.x] + s[tid] - v;
}

// ---------------- XCD-partitioned CSR scatter, int2 payload (src, eid) -------
__global__ __launch_bounds__(256) void scatter_pack_kernel(
    const int* __restrict__ src, const int* __restrict__ dst,
    int* __restrict__ cursor, int2* __restrict__ sp, int E) {
    const int range = blockIdx.x & 7;
    const int lo = range * (N_NODES / 8);
    const int hi = lo + (N_NODES / 8);
    int i = (blockIdx.x >> 3) * blockDim.x + threadIdx.x;
    const int stride = (gridDim.x >> 3) * blockDim.x;
    for (; i < E; i += stride) {
        const int d = dst[i];
        if (d >= lo && d < hi) {
            const int pos = atomicAdd(&cursor[d], 1);
            sp[pos] = make_int2(src[i], i);
        }
    }
}

// ---------------- node GEMM: P1 = x @ W1a[0:6] + b1a ----------------
template <int IN, int OUT>
__global__ __launch_bounds__(256) void node_gemm(
    const float* __restrict__ in_, const float* __restrict__ W,
    const float* __restrict__ bias, float* __restrict__ out_, int N) {
    int n = blockIdx.x * blockDim.x + threadIdx.x;
    if (n >= N) return;
    const float* row = in_ + (size_t)n * IN;
    float v[IN];
#pragma unroll
    for (int k = 0; k < IN; ++k) v[k] = row[k];
    float* orow = out_ + (size_t)n * OUT;
    for (int g = 0; g < OUT / 4; ++g) {   // rolled: weights via uniform s_load
        float a0 = bias[4 * g + 0], a1 = bias[4 * g + 1];
        float a2 = bias[4 * g + 2], a3 = bias[4 * g + 3];
#pragma unroll
        for (int k = 0; k < IN; ++k) {
            const float m = v[k];
            const float* w = &W[k * OUT + 4 * g];
            a0 = fmaf(m, w[0], a0);
            a1 = fmaf(m, w[1], a1);
            a2 = fmaf(m, w[2], a2);
            a3 = fmaf(m, w[3], a3);
        }
        ((float4*)orow)[g] = make_float4(a0, a1, a2, a3);
    }
}

// ---------------- fused layer: CSR aggregate + GEMM epilogue -----------------
// Wave per node (DIN=64) / per node-pair (DIN=32); lane = column.
// agg: sum_e relu(P[src_e,c] + ea_e @ We[:,c]), unroll 4 (independent gathers).
// epi: t=sum*inv; m = t@Wb + bb*mask; LAST ? out=m : out = relu(m)@Wn + bn.
template <int DIN, int DNEXT, bool LAST>
__global__ __launch_bounds__(256) void fused_agg(
    const float* __restrict__ P,     // [N,DIN]
    const int2* __restrict__ sp,     // [E] CSR-ordered (src, eid)
    const float* __restrict__ ea,    // [E,3] original order
    const int* __restrict__ cursor, const int* __restrict__ cnt,
    const float* __restrict__ inv,
    const float* __restrict__ We,    // [3,DIN]
    const float* __restrict__ Wb,    // [DIN,DIN]
    const float* __restrict__ bb,
    const float* __restrict__ Wn,    // [DIN,DNEXT] (unused if LAST)
    const float* __restrict__ bn,
    float* __restrict__ Pout, int N) {
    constexpr int NPW = 64 / DIN;
    const int lane = threadIdx.x & 63;
    const int w    = threadIdx.x >> 6;
    const int c    = lane % DIN;
    const int sub  = lane / DIN;
    const int n    = (blockIdx.x * 4 + w) * NPW + sub;

    __shared__ __align__(16) float lrow[4][64];

    const float we0 = We[c], we1 = We[DIN + c], we2 = We[2 * DIN + c];
    const int end   = cursor[n];
    const int count = cnt[n];
    int j = end - count;
    const float s_inv = inv[n];
    const float mask  = (s_inv != 0.0f) ? 1.0f : 0.0f;

    float sum = 0.0f;
    for (; j + 4 <= end; j += 4) {
        const int2 e0 = sp[j];
        const int2 e1 = sp[j + 1];
        const int2 e2 = sp[j + 2];
        const int2 e3 = sp[j + 3];
        const float p0 = P[(size_t)e0.x * DIN + c];
        const float p1 = P[(size_t)e1.x * DIN + c];
        const float p2 = P[(size_t)e2.x * DIN + c];
        const float p3 = P[(size_t)e3.x * DIN + c];
        const float2 a0 = *(const float2*)&ea[3 * (size_t)e0.y];
        const float2 a1 = *(const float2*)&ea[3 * (size_t)e1.y];
        const float2 a2 = *(const float2*)&ea[3 * (size_t)e2.y];
        const float2 a3 = *(const float2*)&ea[3 * (size_t)e3.y];
        const float z0 = ea[3 * (size_t)e0.y + 2];
        const float z1 = ea[3 * (size_t)e1.y + 2];
        const float z2 = ea[3 * (size_t)e2.y + 2];
        const float z3 = ea[3 * (size_t)e3.y + 2];
        const float h0 = fmaf(z0, we2, fmaf(a0.y, we1, fmaf(a0.x, we0, p0)));
        const float h1 = fmaf(z1, we2, fmaf(a1.y, we1, fmaf(a1.x, we0, p1)));
        const float h2 = fmaf(z2, we2, fmaf(a2.y, we1, fmaf(a2.x, we0, p2)));
        const float h3 = fmaf(z3, we2, fmaf(a3.y, we1, fmaf(a3.x, we0, p3)));
        sum += fmaxf(h0, 0.0f) + fmaxf(h1, 0.0f);
        sum += fmaxf(h2, 0.0f) + fmaxf(h3, 0.0f);
    }
    for (; j < end; ++j) {
        const int2 e0 = sp[j];
        const float p0 = P[(size_t)e0.x * DIN + c];
        const float2 a0 = *(const float2*)&ea[3 * (size_t)e0.y];
        const float z0 = ea[3 * (size_t)e0.y + 2];
        sum += fmaxf(fmaf(z0, we2, fmaf(a0.y, we1, fmaf(a0.x, we0, p0))), 0.0f);
    }

    const float t = sum * s_inv;
    lrow[w][lane] = t;
    __builtin_amdgcn_wave_barrier();
    float m = bb[c] * mask;
#pragma unroll
    for (int q = 0; q < DIN / 4; ++q) {
        const float4 r = *(const float4*)&lrow[w][sub * DIN + 4 * q];
        m = fmaf(r.x, Wb[(4 * q + 0) * DIN + c], m);
        m = fmaf(r.y, Wb[(4 * q + 1) * DIN + c], m);
        m = fmaf(r.z, Wb[(4 * q + 2) * DIN + c], m);
        m = fmaf(r.w, Wb[(4 * q + 3) * DIN + c], m);
    }
    if constexpr (LAST) {
        Pout[(size_t)n * DIN + c] = m;
    } else {
        m = fmaxf(m, 0.0f);
        __builtin_amdgcn_wave_barrier();
        lrow[w][lane] = m;
        __builtin_amdgcn_wave_barrier();
        const int c2 = lane % DNEXT;
        float o = bn[c2];
#pragma unroll
        for (int q = 0; q < DIN / 4; ++q) {
            const float4 r = *(const float4*)&lrow[w][4 * q];
            o = fmaf(r.x, Wn[(4 * q + 0) * DNEXT + c2], o);
            o = fmaf(r.y, Wn[(4 * q + 1) * DNEXT + c2], o);
            o = fmaf(r.z, Wn[(4 * q + 2) * DNEXT + c2], o);
            o = fmaf(r.w, Wn[(4 * q + 3) * DNEXT + c2], o);
        }
        if (lane < DNEXT) Pout[(size_t)n * DNEXT + lane] = o;
    }
}

extern "C" void kernel_launch(void* const* d_in, const int* in_sizes, int n_in,
                              void* d_out, int out_size, void* d_ws, size_t ws_size,
                              hipStream_t stream) {
    const float* x   = (const float*)d_in[0];
    const int*   ei  = (const int*)d_in[1];
    const float* ea  = (const float*)d_in[2];
    const float* W1a = (const float*)d_in[3];
    const float* b1a = (const float*)d_in[4];
    const float* W1b = (const float*)d_in[5];
    const float* b1b = (const float*)d_in[6];
    const float* W2a = (const float*)d_in[7];
    const float* b2a = (const float*)d_in[8];
    const float* W2b = (const float*)d_in[9];
    const float* b2b = (const float*)d_in[10];
    const float* W3a = (const float*)d_in[11];
    const float* b3a = (const float*)d_in[12];
    const float* W3b = (const float*)d_in[13];
    const float* b3b = (const float*)d_in[14];

    const int* src = ei;
    const int* dst = ei + N_EDGES;
    float* out = (float*)d_out;

    // workspace (byte offsets), total ~68 MB:
    // cnt 0x0 | inv 0x80000 | bsum 0x100000 | cursor 0x110000 |
    // sp(int2) 0x200000 (12.8MB) | bufA 0xF00000 (25.6MB) | bufB 0x2800000 (25.6MB)
    char* ws = (char*)d_ws;
    int*   cnt    = (int*)(ws);
    float* inv    = (float*)(ws + 0x80000);
    int*   bsum   = (int*)(ws + 0x100000);
    int*   cursor = (int*)(ws + 0x110000);
    int2*  sp     = (int2*)(ws + 0x200000);
    float* bufA   = (float*)(ws + 0xF00000);
    float* bufB   = (float*)(ws + 0x2800000);

    const int NBLK = (N_NODES + 255) / 256;  // 391

    // graph preprocessing (shared by all 3 layers)
    hipMemsetAsync(cnt, 0, N_NODES * sizeof(int), stream);
    degree_kernel<<<2048, 256, 0, stream>>>(dst, cnt, N_EDGES);
    inv_kernel<<<NBLK, 256, 0, stream>>>(cnt, inv, N_NODES);
    block_sum_kernel<<<NBLK, 256, 0, stream>>>(cnt, bsum, N_NODES);
    scan_bsum_kernel<<<1, 512, 0, stream>>>(bsum, NBLK);
    make_cursor_kernel<<<NBLK, 256, 0, stream>>>(cnt, bsum, cursor, N_NODES);
    scatter_pack_kernel<<<2048, 256, 0, stream>>>(src, dst, cursor, sp, N_EDGES);
    // cursor[n] = end offset of node n's CSR range

    // P1 = x @ W1a[0:6] + b1a  -> bufA
    node_gemm<6, 64><<<NBLK, 256, 0, stream>>>(x, W1a, b1a, bufA, N_NODES);

    // layer 1: gather bufA, epilogue W1b+b1b, relu, W2a+b2a -> bufB (= P2)
    fused_agg<64, 64, false><<<N_NODES / 4, 256, 0, stream>>>(
        bufA, sp, ea, cursor, cnt, inv, W1a + 6 * 64, W1b, b1b, W2a, b2a, bufB, N_NODES);
    // layer 2: gather bufB, epilogue W2b+b2b, relu, W3a+b3a -> bufA (= P3, [N,32])
    fused_agg<64, 32, false><<<N_NODES / 4, 256, 0, stream>>>(
        bufB, sp, ea, cursor, cnt, inv, W2a + 64 * 64, W2b, b2b, W3a, b3a, bufA, N_NODES);
    // layer 3: gather bufA (32-wide), final W3b+b3b -> out
    fused_agg<32, 32, true><<<N_NODES / 8, 256, 0, stream>>>(
        bufA, sp, ea, cursor, cnt, inv, W3a + 64 * 32, W3b, b3b, nullptr, nullptr, out, N_NODES);
}

// Round 7
// 519.279 us; speedup vs baseline: 5.5186x; 1.1232x over previous
//
#include <hip/hip_runtime.h>
#include <hip/hip_fp16.h>

#define N_NODES 100000
#define N_EDGES 1600000

// ---------------- degree ----------------
__global__ __launch_bounds__(256) void degree_kernel(const int* __restrict__ dst,
                                                     int* __restrict__ cnt, int E) {
    int i = blockIdx.x * blockDim.x + threadIdx.x;
    int stride = gridDim.x * blockDim.x;
    for (; i < E; i += stride) atomicAdd(&cnt[dst[i]], 1);
}

__global__ __launch_bounds__(256) void inv_kernel(const int* __restrict__ cnt,
                                                  float* __restrict__ inv, int N) {
    int i = blockIdx.x * blockDim.x + threadIdx.x;
    if (i < N) inv[i] = (cnt[i] > 0) ? (1.0f / (float)cnt[i]) : 0.0f;
}

// ---------------- hierarchical exclusive scan (cnt -> cursor) ----------------
__global__ __launch_bounds__(256) void block_sum_kernel(const int* __restrict__ cnt,
                                                        int* __restrict__ bsum, int N) {
    __shared__ int s[256];
    const int tid = threadIdx.x;
    const int i = blockIdx.x * 256 + tid;
    s[tid] = (i < N) ? cnt[i] : 0;
    __syncthreads();
#pragma unroll
    for (int d = 128; d > 0; d >>= 1) {
        if (tid < d) s[tid] += s[tid + d];
        __syncthreads();
    }
    if (tid == 0) bsum[blockIdx.x] = s[0];
}

__global__ __launch_bounds__(512) void scan_bsum_kernel(int* __restrict__ bsum, int NB) {
    __shared__ int s[512];
    const int tid = threadIdx.x;
    const int v = (tid < NB) ? bsum[tid] : 0;
    s[tid] = v;
    __syncthreads();
    for (int d = 1; d < 512; d <<= 1) {
        const int t = (tid >= d) ? s[tid - d] : 0;
        __syncthreads();
        s[tid] += t;
        __syncthreads();
    }
    if (tid < NB) bsum[tid] = s[tid] - v;  // exclusive
}

__global__ __launch_bounds__(256) void make_cursor_kernel(const int* __restrict__ cnt,
                                                          const int* __restrict__ bsum,
                                                          int* __restrict__ cursor, int N) {
    __shared__ int s[256];
    const int tid = threadIdx.x;
    const int i = blockIdx.x * 256 + tid;
    const int v = (i < N) ? cnt[i] : 0;
    s[tid] = v;
    __syncthreads();
    for (int d = 1; d < 256; d <<= 1) {
        const int t = (tid >= d) ? s[tid - d] : 0;
        __syncthreads();
        s[tid] += t;
        __syncthreads();
    }
    if (i < N) cursor[i] = bsum[blockIdx.x] + s[tid] - v;
}

// ---------------- XCD-partitioned CSR scatter, float4 payload ----------------
// spf[pos] = (src, ea0, ea1, ea2): aggregation reads ea sequentially in CSR
// order (kills the random 64B ea line per edge). blockIdx%8 dst-range
// partitioning lets one XCD's L2 merge the partial-line payload writes.
__global__ __launch_bounds__(256) void scatter_pack_kernel(
    const int* __restrict__ src, const int* __restrict__ dst,
    const float* __restrict__ ea,
    int* __restrict__ cursor, float4* __restrict__ spf, int E) {
    const int range = blockIdx.x & 7;
    const int lo = range * (N_NODES / 8);
    const int hi = lo + (N_NODES / 8);
    int i = (blockIdx.x >> 3) * blockDim.x + threadIdx.x;
    const int stride = (gridDim.x >> 3) * blockDim.x;
    for (; i < E; i += stride) {
        const int d = dst[i];
        if (d >= lo && d < hi) {
            const int pos = atomicAdd(&cursor[d], 1);
            spf[pos] = make_float4(__int_as_float(src[i]),
                                   ea[3 * (size_t)i + 0],
                                   ea[3 * (size_t)i + 1],
                                   ea[3 * (size_t)i + 2]);
        }
    }
}

// ---------------- node GEMM: P1(half) = x @ W1a[0:6] + b1a ----------------
__global__ __launch_bounds__(256) void node_gemm6h(
    const float* __restrict__ x, const float* __restrict__ W,
    const float* __restrict__ bias, __half* __restrict__ out_, int N) {
    int n = blockIdx.x * blockDim.x + threadIdx.x;
    if (n >= N) return;
    const float* row = x + (size_t)n * 6;
    float v[6];
#pragma unroll
    for (int k = 0; k < 6; ++k) v[k] = row[k];
    __half2* orow = (__half2*)(out_ + (size_t)n * 64);
    for (int g = 0; g < 16; ++g) {   // rolled: weights via uniform s_load
        float a0 = bias[4 * g + 0], a1 = bias[4 * g + 1];
        float a2 = bias[4 * g + 2], a3 = bias[4 * g + 3];
#pragma unroll
        for (int k = 0; k < 6; ++k) {
            const float m = v[k];
            const float* w = &W[k * 64 + 4 * g];
            a0 = fmaf(m, w[0], a0);
            a1 = fmaf(m, w[1], a1);
            a2 = fmaf(m, w[2], a2);
            a3 = fmaf(m, w[3], a3);
        }
        orow[2 * g]     = __floats2half2_rn(a0, a1);
        orow[2 * g + 1] = __floats2half2_rn(a2, a3);
    }
}

// ---------------- fused layer: CSR aggregate + GEMM epilogue -----------------
// Wave per node (DIN=64) / node-pair (DIN=32); lane = column.
// agg: sum_e relu(P[src_e,c] + ea_e @ We[:,c]); P gathered as half (INH) or
// float; ea comes from the streamed payload. Unroll 4 = independent gathers.
// epi: t=sum*inv; m = t@Wb + bb*mask; LAST ? out=m : out = relu(m)@Wn + bn.
template <int DIN, int DNEXT, bool LAST, bool INH, bool OUTH>
__global__ __launch_bounds__(256) void fused_agg(
    const void* __restrict__ Pv,     // [N,DIN] half or float
    const float4* __restrict__ spf,  // [E] CSR-ordered (src, ea0, ea1, ea2)
    const int* __restrict__ cursor, const int* __restrict__ cnt,
    const float* __restrict__ inv,
    const float* __restrict__ We,    // [3,DIN]
    const float* __restrict__ Wb,    // [DIN,DIN]
    const float* __restrict__ bb,
    const float* __restrict__ Wn,    // [DIN,DNEXT] (unused if LAST)
    const float* __restrict__ bn,
    void* __restrict__ Poutv, int N) {
    constexpr int NPW = 64 / DIN;
    const float*  Pf = (const float*)Pv;
    const __half* Ph = (const __half*)Pv;
    const int lane = threadIdx.x & 63;
    const int w    = threadIdx.x >> 6;
    const int c    = lane % DIN;
    const int sub  = lane / DIN;
    const int n    = (blockIdx.x * 4 + w) * NPW + sub;

    __shared__ __align__(16) float lrow[4][64];

    const float we0 = We[c], we1 = We[DIN + c], we2 = We[2 * DIN + c];
    const int end   = cursor[n];
    const int count = cnt[n];
    int j = end - count;
    const float s_inv = inv[n];
    const float mask  = (s_inv != 0.0f) ? 1.0f : 0.0f;

    float sum = 0.0f;
    for (; j + 4 <= end; j += 4) {
        const float4 f0 = spf[j];
        const float4 f1 = spf[j + 1];
        const float4 f2 = spf[j + 2];
        const float4 f3 = spf[j + 3];
        const size_t i0 = (size_t)__float_as_int(f0.x) * DIN + c;
        const size_t i1 = (size_t)__float_as_int(f1.x) * DIN + c;
        const size_t i2 = (size_t)__float_as_int(f2.x) * DIN + c;
        const size_t i3 = (size_t)__float_as_int(f3.x) * DIN + c;
        const float p0 = INH ? __half2float(Ph[i0]) : Pf[i0];
        const float p1 = INH ? __half2float(Ph[i1]) : Pf[i1];
        const float p2 = INH ? __half2float(Ph[i2]) : Pf[i2];
        const float p3 = INH ? __half2float(Ph[i3]) : Pf[i3];
        const float h0 = fmaf(f0.w, we2, fmaf(f0.z, we1, fmaf(f0.y, we0, p0)));
        const float h1 = fmaf(f1.w, we2, fmaf(f1.z, we1, fmaf(f1.y, we0, p1)));
        const float h2 = fmaf(f2.w, we2, fmaf(f2.z, we1, fmaf(f2.y, we0, p2)));
        const float h3 = fmaf(f3.w, we2, fmaf(f3.z, we1, fmaf(f3.y, we0, p3)));
        sum += fmaxf(h0, 0.0f) + fmaxf(h1, 0.0f);
        sum += fmaxf(h2, 0.0f) + fmaxf(h3, 0.0f);
    }
    for (; j < end; ++j) {
        const float4 f0 = spf[j];
        const size_t i0 = (size_t)__float_as_int(f0.x) * DIN + c;
        const float p0 = INH ? __half2float(Ph[i0]) : Pf[i0];
        sum += fmaxf(fmaf(f0.w, we2, fmaf(f0.z, we1, fmaf(f0.y, we0, p0))), 0.0f);
    }

    const float t = sum * s_inv;
    lrow[w][lane] = t;
    __builtin_amdgcn_wave_barrier();
    float m = bb[c] * mask;
#pragma unroll
    for (int q = 0; q < DIN / 4; ++q) {
        const float4 r = *(const float4*)&lrow[w][sub * DIN + 4 * q];
        m = fmaf(r.x, Wb[(4 * q + 0) * DIN + c], m);
        m = fmaf(r.y, Wb[(4 * q + 1) * DIN + c], m);
        m = fmaf(r.z, Wb[(4 * q + 2) * DIN + c], m);
        m = fmaf(r.w, Wb[(4 * q + 3) * DIN + c], m);
    }
    if constexpr (LAST) {
        ((float*)Poutv)[(size_t)n * DIN + c] = m;
    } else {
        m = fmaxf(m, 0.0f);
        __builtin_amdgcn_wave_barrier();
        lrow[w][lane] = m;
        __builtin_amdgcn_wave_barrier();
        const int c2 = lane % DNEXT;
        float o = bn[c2];
#pragma unroll
        for (int q = 0; q < DIN / 4; ++q) {
            const float4 r = *(const float4*)&lrow[w][4 * q];
            o = fmaf(r.x, Wn[(4 * q + 0) * DNEXT + c2], o);
            o = fmaf(r.y, Wn[(4 * q + 1) * DNEXT + c2], o);
            o = fmaf(r.z, Wn[(4 * q + 2) * DNEXT + c2], o);
            o = fmaf(r.w, Wn[(4 * q + 3) * DNEXT + c2], o);
        }
        if (lane < DNEXT) {
            if constexpr (OUTH)
                ((__half*)Poutv)[(size_t)n * DNEXT + lane] = __float2half_rn(o);
            else
                ((float*)Poutv)[(size_t)n * DNEXT + lane] = o;
        }
    }
}

extern "C" void kernel_launch(void* const* d_in, const int* in_sizes, int n_in,
                              void* d_out, int out_size, void* d_ws, size_t ws_size,
                              hipStream_t stream) {
    const float* x   = (const float*)d_in[0];
    const int*   ei  = (const int*)d_in[1];
    const float* ea  = (const float*)d_in[2];
    const float* W1a = (const float*)d_in[3];
    const float* b1a = (const float*)d_in[4];
    const float* W1b = (const float*)d_in[5];
    const float* b1b = (const float*)d_in[6];
    const float* W2a = (const float*)d_in[7];
    const float* b2a = (const float*)d_in[8];
    const float* W2b = (const float*)d_in[9];
    const float* b2b = (const float*)d_in[10];
    const float* W3a = (const float*)d_in[11];
    const float* b3a = (const float*)d_in[12];
    const float* W3b = (const float*)d_in[13];
    const float* b3b = (const float*)d_in[14];

    const int* src = ei;
    const int* dst = ei + N_EDGES;
    float* out = (float*)d_out;

    // workspace (byte offsets), total ~68.2 MB (< proven 70MiB floor):
    // cnt 0x0 | inv 0x80000 | bsum 0x100000 | cursor 0x110000 |
    // spf(float4) 0x200000 (25.6MB) | PH1(half) 0x1B00000 (12.8MB) |
    // PH2(half) 0x2800000 (12.8MB) | P3(f32) 0x3500000 (12.8MB)
    char* ws = (char*)d_ws;
    int*    cnt    = (int*)(ws);
    float*  inv    = (float*)(ws + 0x80000);
    int*    bsum   = (int*)(ws + 0x100000);
    int*    cursor = (int*)(ws + 0x110000);
    float4* spf    = (float4*)(ws + 0x200000);
    __half* PH1    = (__half*)(ws + 0x1B00000);
    __half* PH2    = (__half*)(ws + 0x2800000);
    float*  P3     = (float*)(ws + 0x3500000);

    const int NBLK = (N_NODES + 255) / 256;  // 391

    // graph preprocessing (shared by all 3 layers)
    hipMemsetAsync(cnt, 0, N_NODES * sizeof(int), stream);
    degree_kernel<<<2048, 256, 0, stream>>>(dst, cnt, N_EDGES);
    inv_kernel<<<NBLK, 256, 0, stream>>>(cnt, inv, N_NODES);
    block_sum_kernel<<<NBLK, 256, 0, stream>>>(cnt, bsum, N_NODES);
    scan_bsum_kernel<<<1, 512, 0, stream>>>(bsum, NBLK);
    make_cursor_kernel<<<NBLK, 256, 0, stream>>>(cnt, bsum, cursor, N_NODES);
    scatter_pack_kernel<<<2048, 256, 0, stream>>>(src, dst, ea, cursor, spf, N_EDGES);
    // cursor[n] = end offset of node n's CSR range

    // P1 = half(x @ W1a[0:6] + b1a)
    node_gemm6h<<<NBLK, 256, 0, stream>>>(x, W1a, b1a, PH1, N_NODES);

    // layer 1: gather PH1(half), epilogue W1b+b1b, relu, W2a+b2a -> PH2(half)
    fused_agg<64, 64, false, true, true><<<N_NODES / 4, 256, 0, stream>>>(
        PH1, spf, cursor, cnt, inv, W1a + 6 * 64, W1b, b1b, W2a, b2a, PH2, N_NODES);
    // layer 2: gather PH2(half), epilogue W2b+b2b, relu, W3a+b3a -> P3(f32,[N,32])
    fused_agg<64, 32, false, true, false><<<N_NODES / 4, 256, 0, stream>>>(
        PH2, spf, cursor, cnt, inv, W2a + 64 * 64, W2b, b2b, W3a, b3a, P3, N_NODES);
    // layer 3: gather P3(f32, 32-wide), final W3b+b3b -> out
    fused_agg<32, 32, true, false, false><<<N_NODES / 8, 256, 0, stream>>>(
        P3, spf, cursor, cnt, inv, W3a + 64 * 32, W3b, b3b, nullptr, nullptr, out, N_NODES);
}

// Round 8
// 490.057 us; speedup vs baseline: 5.8476x; 1.0596x over previous
//
#include <hip/hip_runtime.h>
#include <hip/hip_fp16.h>

#define N_NODES 100000
#define N_EDGES 1600000

// ---------------- degree ----------------
__global__ __launch_bounds__(256) void degree_kernel(const int* __restrict__ dst,
                                                     int* __restrict__ cnt, int E) {
    int i = blockIdx.x * blockDim.x + threadIdx.x;
    int stride = gridDim.x * blockDim.x;
    for (; i < E; i += stride) atomicAdd(&cnt[dst[i]], 1);
}

__global__ __launch_bounds__(256) void inv_kernel(const int* __restrict__ cnt,
                                                  float* __restrict__ inv, int N) {
    int i = blockIdx.x * blockDim.x + threadIdx.x;
    if (i < N) inv[i] = (cnt[i] > 0) ? (1.0f / (float)cnt[i]) : 0.0f;
}

// ---------------- hierarchical exclusive scan (cnt -> cursor) ----------------
__global__ __launch_bounds__(256) void block_sum_kernel(const int* __restrict__ cnt,
                                                        int* __restrict__ bsum, int N) {
    __shared__ int s[256];
    const int tid = threadIdx.x;
    const int i = blockIdx.x * 256 + tid;
    s[tid] = (i < N) ? cnt[i] : 0;
    __syncthreads();
#pragma unroll
    for (int d = 128; d > 0; d >>= 1) {
        if (tid < d) s[tid] += s[tid + d];
        __syncthreads();
    }
    if (tid == 0) bsum[blockIdx.x] = s[0];
}

__global__ __launch_bounds__(512) void scan_bsum_kernel(int* __restrict__ bsum, int NB) {
    __shared__ int s[512];
    const int tid = threadIdx.x;
    const int v = (tid < NB) ? bsum[tid] : 0;
    s[tid] = v;
    __syncthreads();
    for (int d = 1; d < 512; d <<= 1) {
        const int t = (tid >= d) ? s[tid - d] : 0;
        __syncthreads();
        s[tid] += t;
        __syncthreads();
    }
    if (tid < NB) bsum[tid] = s[tid] - v;  // exclusive
}

__global__ __launch_bounds__(256) void make_cursor_kernel(const int* __restrict__ cnt,
                                                          const int* __restrict__ bsum,
                                                          int* __restrict__ cursor, int N) {
    __shared__ int s[256];
    const int tid = threadIdx.x;
    const int i = blockIdx.x * 256 + tid;
    const int v = (i < N) ? cnt[i] : 0;
    s[tid] = v;
    __syncthreads();
    for (int d = 1; d < 256; d <<= 1) {
        const int t = (tid >= d) ? s[tid - d] : 0;
        __syncthreads();
        s[tid] += t;
        __syncthreads();
    }
    if (i < N) cursor[i] = bsum[blockIdx.x] + s[tid] - v;
}

// ---------------- XCD-partitioned CSR scatter, float4 payload ----------------
__global__ __launch_bounds__(256) void scatter_pack_kernel(
    const int* __restrict__ src, const int* __restrict__ dst,
    const float* __restrict__ ea,
    int* __restrict__ cursor, float4* __restrict__ spf, int E) {
    const int range = blockIdx.x & 7;
    const int lo = range * (N_NODES / 8);
    const int hi = lo + (N_NODES / 8);
    int i = (blockIdx.x >> 3) * blockDim.x + threadIdx.x;
    const int stride = (gridDim.x >> 3) * blockDim.x;
    for (; i < E; i += stride) {
        const int d = dst[i];
        if (d >= lo && d < hi) {
            const int pos = atomicAdd(&cursor[d], 1);
            spf[pos] = make_float4(__int_as_float(src[i]),
                                   ea[3 * (size_t)i + 0],
                                   ea[3 * (size_t)i + 1],
                                   ea[3 * (size_t)i + 2]);
        }
    }
}

// ---------------- node GEMM: P1(half) = x @ W1a[0:6] + b1a ----------------
__global__ __launch_bounds__(256) void node_gemm6h(
    const float* __restrict__ x, const float* __restrict__ W,
    const float* __restrict__ bias, __half* __restrict__ out_, int N) {
    int n = blockIdx.x * blockDim.x + threadIdx.x;
    if (n >= N) return;
    const float* row = x + (size_t)n * 6;
    float v[6];
#pragma unroll
    for (int k = 0; k < 6; ++k) v[k] = row[k];
    __half2* orow = (__half2*)(out_ + (size_t)n * 64);
    for (int g = 0; g < 16; ++g) {
        float a0 = bias[4 * g + 0], a1 = bias[4 * g + 1];
        float a2 = bias[4 * g + 2], a3 = bias[4 * g + 3];
#pragma unroll
        for (int k = 0; k < 6; ++k) {
            const float m = v[k];
            const float* w = &W[k * 64 + 4 * g];
            a0 = fmaf(m, w[0], a0);
            a1 = fmaf(m, w[1], a1);
            a2 = fmaf(m, w[2], a2);
            a3 = fmaf(m, w[3], a3);
        }
        orow[2 * g]     = __floats2half2_rn(a0, a1);
        orow[2 * g + 1] = __floats2half2_rn(a2, a3);
    }
}

// ---------------- fused layer, DIN=64 fp16: quarter-wave-per-edge gather -----
// Wave = 1 node. Quarter q (16 lanes) owns edge j+q; lane p holds cols 4p..4p+3
// (half4 = 8B load -> 16 lanes cover the 128B row). One gather instruction per
// 4 edges. Column sums reduced across quarters via __shfl_xor(16|32).
// epi: t=sum*inv; m = t@Wb + bb*mask; relu; o = m@Wn + bn -> Pout.
template <int DNEXT, bool OUTH>
__global__ __launch_bounds__(256) void fused_agg64(
    const __half* __restrict__ P,    // [N,64] half
    const float4* __restrict__ spf,  // [E] CSR-ordered (src, ea0, ea1, ea2)
    const int* __restrict__ cursor, const int* __restrict__ cnt,
    const float* __restrict__ inv,
    const float* __restrict__ We,    // [3,64]
    const float* __restrict__ Wb,    // [64,64]
    const float* __restrict__ bb,
    const float* __restrict__ Wn,    // [64,DNEXT]
    const float* __restrict__ bn,
    void* __restrict__ Poutv, int N) {
    const int lane = threadIdx.x & 63;
    const int w    = threadIdx.x >> 6;
    const int q    = lane >> 4;
    const int p    = lane & 15;
    const int n    = blockIdx.x * 4 + w;

    __shared__ __align__(16) float lrow[4][64];

    float we0[4], we1[4], we2[4];
#pragma unroll
    for (int k = 0; k < 4; ++k) {
        we0[k] = We[0 * 64 + 4 * p + k];
        we1[k] = We[1 * 64 + 4 * p + k];
        we2[k] = We[2 * 64 + 4 * p + k];
    }

    const int end   = cursor[n];
    const int count = cnt[n];
    int j = end - count;
    const float s_inv = inv[n];
    const float mask  = (s_inv != 0.0f) ? 1.0f : 0.0f;

    float s0 = 0.f, s1 = 0.f, s2 = 0.f, s3 = 0.f;

#define GRP4H(base)                                                              \
    {                                                                            \
        const float4 f = spf[(base) + q];                                        \
        const ushort4 raw = *(const ushort4*)((const unsigned short*)P +         \
                            ((size_t)__float_as_int(f.x) << 6) + 4 * p);         \
        const float p0 = __half2float(__ushort_as_half(raw.x));                  \
        const float p1 = __half2float(__ushort_as_half(raw.y));                  \
        const float p2 = __half2float(__ushort_as_half(raw.z));                  \
        const float p3 = __half2float(__ushort_as_half(raw.w));                  \
        s0 += fmaxf(fmaf(f.w, we2[0], fmaf(f.z, we1[0], fmaf(f.y, we0[0], p0))), 0.f); \
        s1 += fmaxf(fmaf(f.w, we2[1], fmaf(f.z, we1[1], fmaf(f.y, we0[1], p1))), 0.f); \
        s2 += fmaxf(fmaf(f.w, we2[2], fmaf(f.z, we1[2], fmaf(f.y, we0[2], p2))), 0.f); \
        s3 += fmaxf(fmaf(f.w, we2[3], fmaf(f.z, we1[3], fmaf(f.y, we0[3], p3))), 0.f); \
    }

    for (; j + 8 <= end; j += 8) { GRP4H(j) GRP4H(j + 4) }
    if (j + 4 <= end) { GRP4H(j) j += 4; }
    const int rem = end - j;
    if (q < rem) { GRP4H(j) }
#undef GRP4H

    // reduce across the 4 quarters (butterfly)
    s0 += __shfl_xor(s0, 16); s1 += __shfl_xor(s1, 16);
    s2 += __shfl_xor(s2, 16); s3 += __shfl_xor(s3, 16);
    s0 += __shfl_xor(s0, 32); s1 += __shfl_xor(s1, 32);
    s2 += __shfl_xor(s2, 32); s3 += __shfl_xor(s3, 32);

    if (lane < 16) {
        *(float4*)&lrow[w][4 * p] =
            make_float4(s0 * s_inv, s1 * s_inv, s2 * s_inv, s3 * s_inv);
    }
    __builtin_amdgcn_wave_barrier();

    float m = bb[lane] * mask;
#pragma unroll
    for (int k = 0; k < 16; ++k) {
        const float4 r = *(const float4*)&lrow[w][4 * k];
        m = fmaf(r.x, Wb[(4 * k + 0) * 64 + lane], m);
        m = fmaf(r.y, Wb[(4 * k + 1) * 64 + lane], m);
        m = fmaf(r.z, Wb[(4 * k + 2) * 64 + lane], m);
        m = fmaf(r.w, Wb[(4 * k + 3) * 64 + lane], m);
    }
    m = fmaxf(m, 0.0f);
    __builtin_amdgcn_wave_barrier();
    lrow[w][lane] = m;
    __builtin_amdgcn_wave_barrier();
    const int c2 = lane % DNEXT;
    float o = bn[c2];
#pragma unroll
    for (int k = 0; k < 16; ++k) {
        const float4 r = *(const float4*)&lrow[w][4 * k];
        o = fmaf(r.x, Wn[(4 * k + 0) * DNEXT + c2], o);
        o = fmaf(r.y, Wn[(4 * k + 1) * DNEXT + c2], o);
        o = fmaf(r.z, Wn[(4 * k + 2) * DNEXT + c2], o);
        o = fmaf(r.w, Wn[(4 * k + 3) * DNEXT + c2], o);
    }
    if (lane < DNEXT) {
        if constexpr (OUTH)
            ((__half*)Poutv)[(size_t)n * DNEXT + lane] = __float2half_rn(o);
        else
            ((float*)Poutv)[(size_t)n * DNEXT + lane] = o;
    }
}

// ---------------- fused last layer, DIN=32 fp32 ------------------------------
// Wave = 1 node; quarter per edge; lane p holds cols 2p,2p+1 (float2 = 8B,
// 16 lanes cover the 128B row). Final: out = t@Wb + bb*mask (no relu).
__global__ __launch_bounds__(256) void fused_agg32(
    const float* __restrict__ P,     // [N,32] f32
    const float4* __restrict__ spf,
    const int* __restrict__ cursor, const int* __restrict__ cnt,
    const float* __restrict__ inv,
    const float* __restrict__ We,    // [3,32]
    const float* __restrict__ Wb,    // [32,32]
    const float* __restrict__ bb,
    float* __restrict__ out, int N) {
    const int lane = threadIdx.x & 63;
    const int w    = threadIdx.x >> 6;
    const int q    = lane >> 4;
    const int p    = lane & 15;
    const int n    = blockIdx.x * 4 + w;

    __shared__ __align__(16) float lrow[4][32];

    float we0[2], we1[2], we2[2];
#pragma unroll
    for (int k = 0; k < 2; ++k) {
        we0[k] = We[0 * 32 + 2 * p + k];
        we1[k] = We[1 * 32 + 2 * p + k];
        we2[k] = We[2 * 32 + 2 * p + k];
    }

    const int end   = cursor[n];
    const int count = cnt[n];
    int j = end - count;
    const float s_inv = inv[n];
    const float mask  = (s_inv != 0.0f) ? 1.0f : 0.0f;

    float s0 = 0.f, s1 = 0.f;

#define GRP4F(base)                                                              \
    {                                                                            \
        const float4 f = spf[(base) + q];                                        \
        const float2 pr = *(const float2*)(P +                                   \
                          ((size_t)__float_as_int(f.x) << 5) + 2 * p);           \
        s0 += fmaxf(fmaf(f.w, we2[0], fmaf(f.z, we1[0], fmaf(f.y, we0[0], pr.x))), 0.f); \
        s1 += fmaxf(fmaf(f.w, we2[1], fmaf(f.z, we1[1], fmaf(f.y, we0[1], pr.y))), 0.f); \
    }

    for (; j + 8 <= end; j += 8) { GRP4F(j) GRP4F(j + 4) }
    if (j + 4 <= end) { GRP4F(j) j += 4; }
    const int rem = end - j;
    if (q < rem) { GRP4F(j) }
#undef GRP4F

    s0 += __shfl_xor(s0, 16); s1 += __shfl_xor(s1, 16);
    s0 += __shfl_xor(s0, 32); s1 += __shfl_xor(s1, 32);

    if (lane < 16) {
        *(float2*)&lrow[w][2 * p] = make_float2(s0 * s_inv, s1 * s_inv);
    }
    __builtin_amdgcn_wave_barrier();

    const int c = lane & 31;
    float m = bb[c] * mask;
#pragma unroll
    for (int k = 0; k < 8; ++k) {
        const float4 r = *(const float4*)&lrow[w][4 * k];
        m = fmaf(r.x, Wb[(4 * k + 0) * 32 + c], m);
        m = fmaf(r.y, Wb[(4 * k + 1) * 32 + c], m);
        m = fmaf(r.z, Wb[(4 * k + 2) * 32 + c], m);
        m = fmaf(r.w, Wb[(4 * k + 3) * 32 + c], m);
    }
    if (lane < 32) out[(size_t)n * 32 + c] = m;
}

extern "C" void kernel_launch(void* const* d_in, const int* in_sizes, int n_in,
                              void* d_out, int out_size, void* d_ws, size_t ws_size,
                              hipStream_t stream) {
    const float* x   = (const float*)d_in[0];
    const int*   ei  = (const int*)d_in[1];
    const float* ea  = (const float*)d_in[2];
    const float* W1a = (const float*)d_in[3];
    const float* b1a = (const float*)d_in[4];
    const float* W1b = (const float*)d_in[5];
    const float* b1b = (const float*)d_in[6];
    const float* W2a = (const float*)d_in[7];
    const float* b2a = (const float*)d_in[8];
    const float* W2b = (const float*)d_in[9];
    const float* b2b = (const float*)d_in[10];
    const float* W3a = (const float*)d_in[11];
    const float* b3a = (const float*)d_in[12];
    const float* W3b = (const float*)d_in[13];
    const float* b3b = (const float*)d_in[14];

    const int* src = ei;
    const int* dst = ei + N_EDGES;
    float* out = (float*)d_out;

    // workspace (byte offsets), total ~68.2 MB:
    // cnt 0x0 | inv 0x80000 | bsum 0x100000 | cursor 0x110000 |
    // spf(float4) 0x200000 (25.6MB) | PH1(half) 0x1B00000 (12.8MB) |
    // PH2(half) 0x2800000 (12.8MB) | P3(f32) 0x3500000 (12.8MB)
    char* ws = (char*)d_ws;
    int*    cnt    = (int*)(ws);
    float*  inv    = (float*)(ws + 0x80000);
    int*    bsum   = (int*)(ws + 0x100000);
    int*    cursor = (int*)(ws + 0x110000);
    float4* spf    = (float4*)(ws + 0x200000);
    __half* PH1    = (__half*)(ws + 0x1B00000);
    __half* PH2    = (__half*)(ws + 0x2800000);
    float*  P3     = (float*)(ws + 0x3500000);

    const int NBLK = (N_NODES + 255) / 256;  // 391

    // graph preprocessing (shared by all 3 layers)
    hipMemsetAsync(cnt, 0, N_NODES * sizeof(int), stream);
    degree_kernel<<<2048, 256, 0, stream>>>(dst, cnt, N_EDGES);
    inv_kernel<<<NBLK, 256, 0, stream>>>(cnt, inv, N_NODES);
    block_sum_kernel<<<NBLK, 256, 0, stream>>>(cnt, bsum, N_NODES);
    scan_bsum_kernel<<<1, 512, 0, stream>>>(bsum, NBLK);
    make_cursor_kernel<<<NBLK, 256, 0, stream>>>(cnt, bsum, cursor, N_NODES);
    scatter_pack_kernel<<<2048, 256, 0, stream>>>(src, dst, ea, cursor, spf, N_EDGES);
    // cursor[n] = end offset of node n's CSR range

    // P1 = half(x @ W1a[0:6] + b1a)
    node_gemm6h<<<NBLK, 256, 0, stream>>>(x, W1a, b1a, PH1, N_NODES);

    // layer 1: gather PH1(half), epilogue W1b+b1b, relu, W2a+b2a -> PH2(half)
    fused_agg64<64, true><<<N_NODES / 4, 256, 0, stream>>>(
        PH1, spf, cursor, cnt, inv, W1a + 6 * 64, W1b, b1b, W2a, b2a, PH2, N_NODES);
    // layer 2: gather PH2(half), epilogue W2b+b2b, relu, W3a+b3a -> P3(f32,[N,32])
    fused_agg64<32, false><<<N_NODES / 4, 256, 0, stream>>>(
        PH2, spf, cursor, cnt, inv, W2a + 64 * 64, W2b, b2b, W3a, b3a, P3, N_NODES);
    // layer 3: gather P3(f32, 32-wide), final W3b+b3b -> out
    fused_agg32<<<N_NODES / 4, 256, 0, stream>>>(
        P3, spf, cursor, cnt, inv, W3a + 64 * 32, W3b, b3b, out, N_NODES);
}

// Round 9
// 483.790 us; speedup vs baseline: 5.9234x; 1.0130x over previous
//
#include <hip/hip_runtime.h>
#include <hip/hip_fp16.h>

#define N_NODES 100000
#define N_EDGES 1600000

// ---------------- degree (XCD-partitioned: cnt lines stay in one L2) --------
__global__ __launch_bounds__(256) void degree_kernel(const int* __restrict__ dst,
                                                     int* __restrict__ cnt, int E) {
    const int range = blockIdx.x & 7;
    const int lo = range * (N_NODES / 8);
    const int hi = lo + (N_NODES / 8);
    int i = (blockIdx.x >> 3) * blockDim.x + threadIdx.x;
    const int stride = (gridDim.x >> 3) * blockDim.x;
    for (; i < E; i += stride) {
        const int d = dst[i];
        if (d >= lo && d < hi) atomicAdd(&cnt[d], 1);
    }
}

__global__ __launch_bounds__(256) void inv_kernel(const int* __restrict__ cnt,
                                                  float* __restrict__ inv, int N) {
    int i = blockIdx.x * blockDim.x + threadIdx.x;
    if (i < N) inv[i] = (cnt[i] > 0) ? (1.0f / (float)cnt[i]) : 0.0f;
}

// ---------------- hierarchical exclusive scan (cnt -> cursor) ----------------
__global__ __launch_bounds__(256) void block_sum_kernel(const int* __restrict__ cnt,
                                                        int* __restrict__ bsum, int N) {
    __shared__ int s[256];
    const int tid = threadIdx.x;
    const int i = blockIdx.x * 256 + tid;
    s[tid] = (i < N) ? cnt[i] : 0;
    __syncthreads();
#pragma unroll
    for (int d = 128; d > 0; d >>= 1) {
        if (tid < d) s[tid] += s[tid + d];
        __syncthreads();
    }
    if (tid == 0) bsum[blockIdx.x] = s[0];
}

__global__ __launch_bounds__(512) void scan_bsum_kernel(int* __restrict__ bsum, int NB) {
    __shared__ int s[512];
    const int tid = threadIdx.x;
    const int v = (tid < NB) ? bsum[tid] : 0;
    s[tid] = v;
    __syncthreads();
    for (int d = 1; d < 512; d <<= 1) {
        const int t = (tid >= d) ? s[tid - d] : 0;
        __syncthreads();
        s[tid] += t;
        __syncthreads();
    }
    if (tid < NB) bsum[tid] = s[tid] - v;  // exclusive
}

__global__ __launch_bounds__(256) void make_cursor_kernel(const int* __restrict__ cnt,
                                                          const int* __restrict__ bsum,
                                                          int* __restrict__ cursor, int N) {
    __shared__ int s[256];
    const int tid = threadIdx.x;
    const int i = blockIdx.x * 256 + tid;
    const int v = (i < N) ? cnt[i] : 0;
    s[tid] = v;
    __syncthreads();
    for (int d = 1; d < 256; d <<= 1) {
        const int t = (tid >= d) ? s[tid - d] : 0;
        __syncthreads();
        s[tid] += t;
        __syncthreads();
    }
    if (i < N) cursor[i] = bsum[blockIdx.x] + s[tid] - v;
}

// ---------------- XCD-partitioned CSR scatter, float4 payload ----------------
__global__ __launch_bounds__(256) void scatter_pack_kernel(
    const int* __restrict__ src, const int* __restrict__ dst,
    const float* __restrict__ ea,
    int* __restrict__ cursor, float4* __restrict__ spf, int E) {
    const int range = blockIdx.x & 7;
    const int lo = range * (N_NODES / 8);
    const int hi = lo + (N_NODES / 8);
    int i = (blockIdx.x >> 3) * blockDim.x + threadIdx.x;
    const int stride = (gridDim.x >> 3) * blockDim.x;
    for (; i < E; i += stride) {
        const int d = dst[i];
        if (d >= lo && d < hi) {
            const int pos = atomicAdd(&cursor[d], 1);
            spf[pos] = make_float4(__int_as_float(src[i]),
                                   ea[3 * (size_t)i + 0],
                                   ea[3 * (size_t)i + 1],
                                   ea[3 * (size_t)i + 2]);
        }
    }
}

// ---------------- node GEMM: P1(half) = x @ W1a[0:6] + b1a ----------------
__global__ __launch_bounds__(256) void node_gemm6h(
    const float* __restrict__ x, const float* __restrict__ W,
    const float* __restrict__ bias, __half* __restrict__ out_, int N) {
    int n = blockIdx.x * blockDim.x + threadIdx.x;
    if (n >= N) return;
    const float* row = x + (size_t)n * 6;
    float v[6];
#pragma unroll
    for (int k = 0; k < 6; ++k) v[k] = row[k];
    __half2* orow = (__half2*)(out_ + (size_t)n * 64);
    for (int g = 0; g < 16; ++g) {
        float a0 = bias[4 * g + 0], a1 = bias[4 * g + 1];
        float a2 = bias[4 * g + 2], a3 = bias[4 * g + 3];
#pragma unroll
        for (int k = 0; k < 6; ++k) {
            const float m = v[k];
            const float* w = &W[k * 64 + 4 * g];
            a0 = fmaf(m, w[0], a0);
            a1 = fmaf(m, w[1], a1);
            a2 = fmaf(m, w[2], a2);
            a3 = fmaf(m, w[3], a3);
        }
        orow[2 * g]     = __floats2half2_rn(a0, a1);
        orow[2 * g + 1] = __floats2half2_rn(a2, a3);
    }
}

// ---------------- fused layer, DIN=64 fp16, prefetched quarter-wave gather ---
// Wave = 1 node. Quarter q owns edge (group+q); lane p holds cols 4p..4p+3.
// spf payloads for the NEXT 8-edge group are prefetched while the current
// group's P-gathers are in flight (2 gathers + 2 prefetches outstanding).
template <int DNEXT, bool OUTH>
__global__ __launch_bounds__(256) void fused_agg64(
    const __half* __restrict__ P,    // [N,64] half
    const float4* __restrict__ spf,  // [E] CSR-ordered (src, ea0, ea1, ea2)
    const int* __restrict__ cursor, const int* __restrict__ cnt,
    const float* __restrict__ inv,
    const float* __restrict__ We,    // [3,64]
    const float* __restrict__ Wb,    // [64,64]
    const float* __restrict__ bb,
    const float* __restrict__ Wn,    // [64,DNEXT]
    const float* __restrict__ bn,
    void* __restrict__ Poutv, int N) {
    const int lane = threadIdx.x & 63;
    const int w    = threadIdx.x >> 6;
    const int q    = lane >> 4;
    const int p    = lane & 15;
    const int n    = blockIdx.x * 4 + w;

    __shared__ __align__(16) float lrow[4][64];

    float we0[4], we1[4], we2[4];
#pragma unroll
    for (int k = 0; k < 4; ++k) {
        we0[k] = We[0 * 64 + 4 * p + k];
        we1[k] = We[1 * 64 + 4 * p + k];
        we2[k] = We[2 * 64 + 4 * p + k];
    }

    const int end   = cursor[n];
    const int count = cnt[n];
    int j = end - count;
    const float s_inv = inv[n];
    const float mask  = (s_inv != 0.0f) ? 1.0f : 0.0f;

    float s0 = 0.f, s1 = 0.f, s2 = 0.f, s3 = 0.f;

#define PROC64(f, valid)                                                         \
    {                                                                            \
        const ushort4 raw = *(const ushort4*)((const unsigned short*)P +         \
                            ((size_t)__float_as_int((f).x) << 6) + 4 * p);       \
        const float p0 = __half2float(__ushort_as_half(raw.x));                  \
        const float p1 = __half2float(__ushort_as_half(raw.y));                  \
        const float p2 = __half2float(__ushort_as_half(raw.z));                  \
        const float p3 = __half2float(__ushort_as_half(raw.w));                  \
        const float h0 = fmaxf(fmaf((f).w, we2[0], fmaf((f).z, we1[0], fmaf((f).y, we0[0], p0))), 0.f); \
        const float h1 = fmaxf(fmaf((f).w, we2[1], fmaf((f).z, we1[1], fmaf((f).y, we0[1], p1))), 0.f); \
        const float h2 = fmaxf(fmaf((f).w, we2[2], fmaf((f).z, we1[2], fmaf((f).y, we0[2], p2))), 0.f); \
        const float h3 = fmaxf(fmaf((f).w, we2[3], fmaf((f).z, we1[3], fmaf((f).y, we0[3], p3))), 0.f); \
        if (valid) { s0 += h0; s1 += h1; s2 += h2; s3 += h3; }                   \
    }

    if (count > 0) {
        const int e0 = j + q,     e1 = j + 4 + q;
        float4 f0 = spf[e0 < end ? e0 : end - 1];
        float4 f1 = spf[e1 < end ? e1 : end - 1];
        while (j + 8 < end) {
            const int g0i = j + 8 + q, g1i = j + 12 + q;
            const float4 g0 = spf[g0i < end ? g0i : end - 1];
            const float4 g1 = spf[g1i < end ? g1i : end - 1];
            PROC64(f0, true)
            PROC64(f1, true)
            f0 = g0; f1 = g1; j += 8;
        }
        PROC64(f0, (j + q < end))
        PROC64(f1, (j + 4 + q < end))
    }
#undef PROC64

    // reduce across the 4 quarters (butterfly)
    s0 += __shfl_xor(s0, 16); s1 += __shfl_xor(s1, 16);
    s2 += __shfl_xor(s2, 16); s3 += __shfl_xor(s3, 16);
    s0 += __shfl_xor(s0, 32); s1 += __shfl_xor(s1, 32);
    s2 += __shfl_xor(s2, 32); s3 += __shfl_xor(s3, 32);

    if (lane < 16) {
        *(float4*)&lrow[w][4 * p] =
            make_float4(s0 * s_inv, s1 * s_inv, s2 * s_inv, s3 * s_inv);
    }
    __builtin_amdgcn_wave_barrier();

    float m = bb[lane] * mask;
#pragma unroll
    for (int k = 0; k < 16; ++k) {
        const float4 r = *(const float4*)&lrow[w][4 * k];
        m = fmaf(r.x, Wb[(4 * k + 0) * 64 + lane], m);
        m = fmaf(r.y, Wb[(4 * k + 1) * 64 + lane], m);
        m = fmaf(r.z, Wb[(4 * k + 2) * 64 + lane], m);
        m = fmaf(r.w, Wb[(4 * k + 3) * 64 + lane], m);
    }
    m = fmaxf(m, 0.0f);
    __builtin_amdgcn_wave_barrier();
    lrow[w][lane] = m;
    __builtin_amdgcn_wave_barrier();
    const int c2 = lane % DNEXT;
    float o = bn[c2];
#pragma unroll
    for (int k = 0; k < 16; ++k) {
        const float4 r = *(const float4*)&lrow[w][4 * k];
        o = fmaf(r.x, Wn[(4 * k + 0) * DNEXT + c2], o);
        o = fmaf(r.y, Wn[(4 * k + 1) * DNEXT + c2], o);
        o = fmaf(r.z, Wn[(4 * k + 2) * DNEXT + c2], o);
        o = fmaf(r.w, Wn[(4 * k + 3) * DNEXT + c2], o);
    }
    if (lane < DNEXT) {
        if constexpr (OUTH)
            ((__half*)Poutv)[(size_t)n * DNEXT + lane] = __float2half_rn(o);
        else
            ((float*)Poutv)[(size_t)n * DNEXT + lane] = o;
    }
}

// ---------------- fused last layer, DIN=32 fp16 rows (64B gathers) -----------
// Wave = 1 node; quarter per edge; lane p holds cols 2p,2p+1 (half2 = 4B,
// 16 lanes cover the 64B row). Final: out = t@Wb + bb*mask (no relu).
__global__ __launch_bounds__(256) void fused_agg32h(
    const __half* __restrict__ P,    // [N,32] half
    const float4* __restrict__ spf,
    const int* __restrict__ cursor, const int* __restrict__ cnt,
    const float* __restrict__ inv,
    const float* __restrict__ We,    // [3,32]
    const float* __restrict__ Wb,    // [32,32]
    const float* __restrict__ bb,
    float* __restrict__ out, int N) {
    const int lane = threadIdx.x & 63;
    const int w    = threadIdx.x >> 6;
    const int q    = lane >> 4;
    const int p    = lane & 15;
    const int n    = blockIdx.x * 4 + w;

    __shared__ __align__(16) float lrow[4][32];

    float we0[2], we1[2], we2[2];
#pragma unroll
    for (int k = 0; k < 2; ++k) {
        we0[k] = We[0 * 32 + 2 * p + k];
        we1[k] = We[1 * 32 + 2 * p + k];
        we2[k] = We[2 * 32 + 2 * p + k];
    }

    const int end   = cursor[n];
    const int count = cnt[n];
    int j = end - count;
    const float s_inv = inv[n];
    const float mask  = (s_inv != 0.0f) ? 1.0f : 0.0f;

    float s0 = 0.f, s1 = 0.f;

#define PROC32(f, valid)                                                         \
    {                                                                            \
        const __half2 pr = *(const __half2*)((const __half*)P +                  \
                           ((size_t)__float_as_int((f).x) << 5) + 2 * p);        \
        const float2 pf = __half22float2(pr);                                    \
        const float h0 = fmaxf(fmaf((f).w, we2[0], fmaf((f).z, we1[0], fmaf((f).y, we0[0], pf.x))), 0.f); \
        const float h1 = fmaxf(fmaf((f).w, we2[1], fmaf((f).z, we1[1], fmaf((f).y, we0[1], pf.y))), 0.f); \
        if (valid) { s0 += h0; s1 += h1; }                                       \
    }

    if (count > 0) {
        const int e0 = j + q,     e1 = j + 4 + q;
        float4 f0 = spf[e0 < end ? e0 : end - 1];
        float4 f1 = spf[e1 < end ? e1 : end - 1];
        while (j + 8 < end) {
            const int g0i = j + 8 + q, g1i = j + 12 + q;
            const float4 g0 = spf[g0i < end ? g0i : end - 1];
            const float4 g1 = spf[g1i < end ? g1i : end - 1];
            PROC32(f0, true)
            PROC32(f1, true)
            f0 = g0; f1 = g1; j += 8;
        }
        PROC32(f0, (j + q < end))
        PROC32(f1, (j + 4 + q < end))
    }
#undef PROC32

    s0 += __shfl_xor(s0, 16); s1 += __shfl_xor(s1, 16);
    s0 += __shfl_xor(s0, 32); s1 += __shfl_xor(s1, 32);

    if (lane < 16) {
        *(float2*)&lrow[w][2 * p] = make_float2(s0 * s_inv, s1 * s_inv);
    }
    __builtin_amdgcn_wave_barrier();

    const int c = lane & 31;
    float m = bb[c] * mask;
#pragma unroll
    for (int k = 0; k < 8; ++k) {
        const float4 r = *(const float4*)&lrow[w][4 * k];
        m = fmaf(r.x, Wb[(4 * k + 0) * 32 + c], m);
        m = fmaf(r.y, Wb[(4 * k + 1) * 32 + c], m);
        m = fmaf(r.z, Wb[(4 * k + 2) * 32 + c], m);
        m = fmaf(r.w, Wb[(4 * k + 3) * 32 + c], m);
    }
    if (lane < 32) out[(size_t)n * 32 + c] = m;
}

extern "C" void kernel_launch(void* const* d_in, const int* in_sizes, int n_in,
                              void* d_out, int out_size, void* d_ws, size_t ws_size,
                              hipStream_t stream) {
    const float* x   = (const float*)d_in[0];
    const int*   ei  = (const int*)d_in[1];
    const float* ea  = (const float*)d_in[2];
    const float* W1a = (const float*)d_in[3];
    const float* b1a = (const float*)d_in[4];
    const float* W1b = (const float*)d_in[5];
    const float* b1b = (const float*)d_in[6];
    const float* W2a = (const float*)d_in[7];
    const float* b2a = (const float*)d_in[8];
    const float* W2b = (const float*)d_in[9];
    const float* b2b = (const float*)d_in[10];
    const float* W3a = (const float*)d_in[11];
    const float* b3a = (const float*)d_in[12];
    const float* W3b = (const float*)d_in[13];
    const float* b3b = (const float*)d_in[14];

    const int* src = ei;
    const int* dst = ei + N_EDGES;
    float* out = (float*)d_out;

    // workspace (byte offsets), total ~62 MB:
    // cnt 0x0 | inv 0x80000 | bsum 0x100000 | cursor 0x110000 |
    // spf(float4) 0x200000 (25.6MB) | PH1(half) 0x1B00000 (12.8MB) |
    // PH2(half) 0x2800000 (12.8MB) | P3h(half) 0x3500000 (6.4MB)
    char* ws = (char*)d_ws;
    int*    cnt    = (int*)(ws);
    float*  inv    = (float*)(ws + 0x80000);
    int*    bsum   = (int*)(ws + 0x100000);
    int*    cursor = (int*)(ws + 0x110000);
    float4* spf    = (float4*)(ws + 0x200000);
    __half* PH1    = (__half*)(ws + 0x1B00000);
    __half* PH2    = (__half*)(ws + 0x2800000);
    __half* P3h    = (__half*)(ws + 0x3500000);

    const int NBLK = (N_NODES + 255) / 256;  // 391

    // graph preprocessing (shared by all 3 layers)
    hipMemsetAsync(cnt, 0, N_NODES * sizeof(int), stream);
    degree_kernel<<<2048, 256, 0, stream>>>(dst, cnt, N_EDGES);
    inv_kernel<<<NBLK, 256, 0, stream>>>(cnt, inv, N_NODES);
    block_sum_kernel<<<NBLK, 256, 0, stream>>>(cnt, bsum, N_NODES);
    scan_bsum_kernel<<<1, 512, 0, stream>>>(bsum, NBLK);
    make_cursor_kernel<<<NBLK, 256, 0, stream>>>(cnt, bsum, cursor, N_NODES);
    scatter_pack_kernel<<<2048, 256, 0, stream>>>(src, dst, ea, cursor, spf, N_EDGES);
    // cursor[n] = end offset of node n's CSR range

    // P1 = half(x @ W1a[0:6] + b1a)
    node_gemm6h<<<NBLK, 256, 0, stream>>>(x, W1a, b1a, PH1, N_NODES);

    // layer 1: gather PH1(half), epilogue W1b+b1b, relu, W2a+b2a -> PH2(half)
    fused_agg64<64, true><<<N_NODES / 4, 256, 0, stream>>>(
        PH1, spf, cursor, cnt, inv, W1a + 6 * 64, W1b, b1b, W2a, b2a, PH2, N_NODES);
    // layer 2: gather PH2(half), epilogue W2b+b2b, relu, W3a+b3a -> P3h(half,[N,32])
    fused_agg64<32, true><<<N_NODES / 4, 256, 0, stream>>>(
        PH2, spf, cursor, cnt, inv, W2a + 64 * 64, W2b, b2b, W3a, b3a, P3h, N_NODES);
    // layer 3: gather P3h(half, 32-wide = 64B rows), final W3b+b3b -> out
    fused_agg32h<<<N_NODES / 4, 256, 0, stream>>>(
        P3h, spf, cursor, cnt, inv, W3a + 64 * 32, W3b, b3b, out, N_NODES);
}